// Round 1
// baseline (1718.168 us; speedup 1.0000x reference)
//
#include <hip/hip_runtime.h>
#include <math.h>

#define N_NODES 2048
#define NNE ((long)N_NODES * N_NODES)   // 4,194,304 elems per channel matrix
#define NNE4 (NNE / 4)                  // float4 count

// ---------------- softmax of the three 4x4 weight matrices ----------------
__global__ void softmax3_k(const float* __restrict__ w1,
                           const float* __restrict__ w2,
                           const float* __restrict__ w3,
                           float* __restrict__ fw) {
  int t = threadIdx.x;
  if (t < 12) {
    const float* src = (t < 4) ? w1 : (t < 8) ? w2 : w3;
    int r = t & 3;
    float v0 = src[r * 4 + 0], v1 = src[r * 4 + 1];
    float v2 = src[r * 4 + 2], v3 = src[r * 4 + 3];
    float m = fmaxf(fmaxf(v0, v1), fmaxf(v2, v3));
    float e0 = expf(v0 - m), e1 = expf(v1 - m), e2 = expf(v2 - m), e3 = expf(v3 - m);
    float inv = 1.0f / (e0 + e1 + e2 + e3);
    fw[t * 4 + 0] = e0 * inv; fw[t * 4 + 1] = e1 * inv;
    fw[t * 4 + 2] = e2 * inv; fw[t * 4 + 3] = e3 * inv;
  }
}

// ---------------- support = X @ gcn_w  [2048,256]@[256,128] ----------------
__global__ __launch_bounds__(128)
void support_k(const float* __restrict__ X, const float* __restrict__ W,
               float* __restrict__ sup) {
  __shared__ float Xs[256];
  const int t = threadIdx.x;
  const int m = blockIdx.x;
  Xs[t]       = X[(long)m * 256 + t];
  Xs[t + 128] = X[(long)m * 256 + t + 128];
  __syncthreads();
  float acc = 0.f;
  #pragma unroll 8
  for (int k = 0; k < 256; ++k) acc = fmaf(Xs[k], W[(long)k * 128 + t], acc);
  sup[(long)m * 128 + t] = acc;
}

// ---------------- channel mix: O1[c] = sum_e fw[off1][c][e]*A[e] (opt O2) ----
__global__ __launch_bounds__(256)
void mix_k(const float4* __restrict__ A4, const float* __restrict__ fw,
           float4* __restrict__ O1, float4* __restrict__ O2,
           int c0, int nc, int off1, int off2) {
  long idx = (long)blockIdx.x * 256 + threadIdx.x;
  if (idx >= NNE4) return;
  float4 a0 = A4[idx];
  float4 a1 = A4[NNE4 + idx];
  float4 a2 = A4[2 * NNE4 + idx];
  float4 a3 = A4[3 * NNE4 + idx];
  #pragma unroll
  for (int ci = 0; ci < 4; ++ci) {
    if (ci >= nc) break;
    int c = c0 + ci;
    const float* wa = fw + off1 + c * 4;
    float4 o;
    o.x = wa[0] * a0.x + wa[1] * a1.x + wa[2] * a2.x + wa[3] * a3.x;
    o.y = wa[0] * a0.y + wa[1] * a1.y + wa[2] * a2.y + wa[3] * a3.y;
    o.z = wa[0] * a0.z + wa[1] * a1.z + wa[2] * a2.z + wa[3] * a3.z;
    o.w = wa[0] * a0.w + wa[1] * a1.w + wa[2] * a2.w + wa[3] * a3.w;
    O1[(long)ci * NNE4 + idx] = o;
    if (O2) {
      const float* wb = fw + off2 + c * 4;
      float4 p;
      p.x = wb[0] * a0.x + wb[1] * a1.x + wb[2] * a2.x + wb[3] * a3.x;
      p.y = wb[0] * a0.y + wb[1] * a1.y + wb[2] * a2.y + wb[3] * a3.y;
      p.z = wb[0] * a0.z + wb[1] * a1.z + wb[2] * a2.z + wb[3] * a3.z;
      p.w = wb[0] * a0.w + wb[1] * a1.w + wb[2] * a2.w + wb[3] * a3.w;
      O2[(long)ci * NNE4 + idx] = p;
    }
  }
}

// ---------------- fp32 SGEMM  C = A@B, per-channel (z), 128x128 tile --------
__global__ __launch_bounds__(256)
void gemm_nn(const float* __restrict__ Ab, const float* __restrict__ Bb,
             float* __restrict__ Cb) {
  const int t = threadIdx.x;
  const long zoff = (long)blockIdx.z * NNE;
  const float* A = Ab + zoff;
  const float* B = Bb + zoff;
  float*       C = Cb + zoff;
  const int i0 = blockIdx.y * 128, j0 = blockIdx.x * 128;
  const int Nn = N_NODES;

  __shared__ float As[16][132];   // [k][i], +4 pad
  __shared__ float Bs[16][128];   // [k][j]

  const int ar = t >> 2;          // 0..63
  const int ak = (t & 3) << 2;    // 0,4,8,12
  const int br = t >> 5;          // 0..7
  const int bj = (t & 31) << 2;   // 0..124

  const float* Ap0 = A + (long)(i0 + ar) * Nn + ak;
  const float* Ap1 = A + (long)(i0 + 64 + ar) * Nn + ak;
  const float* Bp0 = B + (long)br * Nn + j0 + bj;
  const float* Bp1 = B + (long)(br + 8) * Nn + j0 + bj;

  float4 a0 = *(const float4*)Ap0;
  float4 a1 = *(const float4*)Ap1;
  float4 b0 = *(const float4*)Bp0;
  float4 b1 = *(const float4*)Bp1;

  const int tx = t & 15, ty = t >> 4;
  float acc[8][8];
  #pragma unroll
  for (int r = 0; r < 8; ++r)
    #pragma unroll
    for (int s = 0; s < 8; ++s) acc[r][s] = 0.f;

  const int nk = Nn / 16;
  for (int kt = 0; kt < nk; ++kt) {
    __syncthreads();
    As[ak + 0][ar] = a0.x; As[ak + 1][ar] = a0.y;
    As[ak + 2][ar] = a0.z; As[ak + 3][ar] = a0.w;
    As[ak + 0][64 + ar] = a1.x; As[ak + 1][64 + ar] = a1.y;
    As[ak + 2][64 + ar] = a1.z; As[ak + 3][64 + ar] = a1.w;
    *(float4*)&Bs[br][bj]     = b0;
    *(float4*)&Bs[br + 8][bj] = b1;
    __syncthreads();
    if (kt + 1 < nk) {
      Ap0 += 16; Ap1 += 16;
      Bp0 += (long)16 * Nn; Bp1 += (long)16 * Nn;
      a0 = *(const float4*)Ap0; a1 = *(const float4*)Ap1;
      b0 = *(const float4*)Bp0; b1 = *(const float4*)Bp1;
    }
    #pragma unroll
    for (int k = 0; k < 16; ++k) {
      float av[8], bv[8];
      *(float4*)&av[0] = *(const float4*)&As[k][ty * 8];
      *(float4*)&av[4] = *(const float4*)&As[k][ty * 8 + 4];
      *(float4*)&bv[0] = *(const float4*)&Bs[k][tx * 8];
      *(float4*)&bv[4] = *(const float4*)&Bs[k][tx * 8 + 4];
      #pragma unroll
      for (int r = 0; r < 8; ++r)
        #pragma unroll
        for (int s = 0; s < 8; ++s)
          acc[r][s] = fmaf(av[r], bv[s], acc[r][s]);
    }
  }
  float* Cr = C + (long)(i0 + ty * 8) * Nn + j0 + tx * 8;
  #pragma unroll
  for (int r = 0; r < 8; ++r) {
    float4 o0 = make_float4(acc[r][0], acc[r][1], acc[r][2], acc[r][3]);
    float4 o1 = make_float4(acc[r][4], acc[r][5], acc[r][6], acc[r][7]);
    *(float4*)(Cr + (long)r * Nn)     = o0;
    *(float4*)(Cr + (long)r * Nn + 4) = o1;
  }
}

// ---------------- row degree -> d = 1/sqrt(1 + rowsum(H2)) ------------------
__global__ __launch_bounds__(256)
void rowsum_k(const float* __restrict__ Hb, float* __restrict__ dvec, int c0) {
  const int t = threadIdx.x;
  const float* R = Hb + (long)blockIdx.y * NNE + (long)blockIdx.x * N_NODES;
  float s = 0.f;
  #pragma unroll
  for (int m = 0; m < 8; ++m) s += R[t + 256 * m];
  for (int off = 32; off > 0; off >>= 1) s += __shfl_down(s, off, 64);
  __shared__ float red[4];
  if ((t & 63) == 0) red[t >> 6] = s;
  __syncthreads();
  if (t == 0) {
    float deg = 1.0f + ((red[0] + red[1]) + (red[2] + red[3]));
    float dd = 1.0f / sqrtf(deg);                 // deg >= 1, never inf
    dvec[(long)(c0 + blockIdx.y) * N_NODES + blockIdx.x] = dd;
  }
}

// ---------------- supd[c][m][f] = d[c][m] * support[m][f] -------------------
__global__ __launch_bounds__(256)
void supd_k(const float4* __restrict__ sup4, const float* __restrict__ dvec,
            float4* __restrict__ out4, int c0) {
  const int c = c0 + blockIdx.y;
  const int idx = blockIdx.x * 256 + threadIdx.x;   // 0..65535 (N*128/4)
  const int m = idx >> 5;
  float dm = dvec[(long)c * N_NODES + m];
  float4 v = sup4[idx];
  v.x *= dm; v.y *= dm; v.z *= dm; v.w *= dm;
  out4[(long)c * (N_NODES * 32) + idx] = v;
}

// ------- out[:, c*128 : (c+1)*128] = relu(d_n*(H2@supd + supd_n) + b) -------
__global__ __launch_bounds__(256)
void gemm_out_k(const float* __restrict__ H2b, const float* __restrict__ supd,
                const float* __restrict__ dvec, const float* __restrict__ bias,
                float* __restrict__ out, int c0) {
  const int t = threadIdx.x;
  const int c = c0 + blockIdx.z;
  const float* A    = H2b + (long)blockIdx.z * NNE;
  const float* Bsup = supd + (long)c * N_NODES * 128;
  const float* dv   = dvec + (long)c * N_NODES;
  const int i0 = blockIdx.x * 32;

  __shared__ float As[32][36];    // [k][i], +4 pad
  __shared__ float Bs[32][128];   // [k][f]

  const int arow = t >> 3;         // 0..31
  const int akq  = (t & 7) << 2;   // 0..28
  const int brow = t >> 5;         // 0..7
  const int bjq  = (t & 31) << 2;  // 0..124
  const int tx = t & 31, ty = t >> 5;

  float acc[4][4];
  #pragma unroll
  for (int r = 0; r < 4; ++r)
    #pragma unroll
    for (int s = 0; s < 4; ++s) acc[r][s] = 0.f;

  const int nk = N_NODES / 32;
  for (int kt = 0; kt < nk; ++kt) {
    const int k0 = kt * 32;
    __syncthreads();
    float4 av4 = *(const float4*)(A + (long)(i0 + arow) * N_NODES + k0 + akq);
    As[akq + 0][arow] = av4.x; As[akq + 1][arow] = av4.y;
    As[akq + 2][arow] = av4.z; As[akq + 3][arow] = av4.w;
    #pragma unroll
    for (int m = 0; m < 4; ++m)
      *(float4*)&Bs[brow + 8 * m][bjq] =
          *(const float4*)(Bsup + (long)(k0 + brow + 8 * m) * 128 + bjq);
    __syncthreads();
    #pragma unroll
    for (int k = 0; k < 32; ++k) {
      float av[4], bv[4];
      *(float4*)&av[0] = *(const float4*)&As[k][ty * 4];
      *(float4*)&bv[0] = *(const float4*)&Bs[k][tx * 4];
      #pragma unroll
      for (int r = 0; r < 4; ++r)
        #pragma unroll
        for (int s = 0; s < 4; ++s)
          acc[r][s] = fmaf(av[r], bv[s], acc[r][s]);
    }
  }
  #pragma unroll
  for (int r = 0; r < 4; ++r) {
    const int i = i0 + ty * 4 + r;
    const float dn = dv[i];
    float4 o;
    o.x = fmaxf(dn * (acc[r][0] + Bsup[(long)i * 128 + tx * 4 + 0]) + bias[tx * 4 + 0], 0.f);
    o.y = fmaxf(dn * (acc[r][1] + Bsup[(long)i * 128 + tx * 4 + 1]) + bias[tx * 4 + 1], 0.f);
    o.z = fmaxf(dn * (acc[r][2] + Bsup[(long)i * 128 + tx * 4 + 2]) + bias[tx * 4 + 2], 0.f);
    o.w = fmaxf(dn * (acc[r][3] + Bsup[(long)i * 128 + tx * 4 + 3]) + bias[tx * 4 + 3], 0.f);
    *(float4*)(out + (long)i * 512 + c * 128 + tx * 4) = o;
  }
}

extern "C" void kernel_launch(void* const* d_in, const int* in_sizes, int n_in,
                              void* d_out, int out_size, void* d_ws, size_t ws_size,
                              hipStream_t stream) {
  const float* A  = (const float*)d_in[0];
  const float* X  = (const float*)d_in[1];
  const float* w1 = (const float*)d_in[2];
  const float* w2 = (const float*)d_in[3];
  const float* w3 = (const float*)d_in[4];
  const float* gw = (const float*)d_in[5];
  const float* gb = (const float*)d_in[6];
  float* out = (float*)d_out;

  float* ws   = (float*)d_ws;
  float* fw   = ws;                       // 64 floats (3x4x4 softmaxed weights)
  float* dvec = ws + 64;                  // 4*2048
  float* sup  = dvec + 4 * N_NODES;       // 2048*128
  float* supd = sup + (long)N_NODES * 128;      // 4*2048*128
  float* big  = supd + (long)4 * N_NODES * 128;

  const long small = 64 + 4 * N_NODES + (long)N_NODES * 128 + (long)4 * N_NODES * 128;
  int nc = 1;
  if (ws_size >= (size_t)(small + 3L * 4 * NNE) * 4) nc = 4;
  else if (ws_size >= (size_t)(small + 3L * 2 * NNE) * 4) nc = 2;

  float* B1 = big;
  float* B2 = B1 + (long)nc * NNE;
  float* B3 = B2 + (long)nc * NNE;

  softmax3_k<<<1, 64, 0, stream>>>(w1, w2, w3, fw);
  support_k<<<N_NODES, 128, 0, stream>>>(X, gw, sup);

  for (int c0 = 0; c0 < 4; c0 += nc) {
    // Ha -> B1, Hb -> B2
    mix_k<<<(int)(NNE4 / 256), 256, 0, stream>>>((const float4*)A, fw,
                                                 (float4*)B1, (float4*)B2,
                                                 c0, nc, 0, 16);
    // H1 = Ha @ Hb -> B3
    gemm_nn<<<dim3(16, 16, nc), 256, 0, stream>>>(B1, B2, B3);
    // Hc -> B1
    mix_k<<<(int)(NNE4 / 256), 256, 0, stream>>>((const float4*)A, fw,
                                                 (float4*)B1, nullptr,
                                                 c0, nc, 32, 0);
    // H2 = H1 @ Hc -> B2
    gemm_nn<<<dim3(16, 16, nc), 256, 0, stream>>>(B3, B1, B2);
    // d[c] from H2 row sums
    rowsum_k<<<dim3(N_NODES, nc), 256, 0, stream>>>(B2, dvec, c0);
    // supd = d * support
    supd_k<<<dim3(256, nc), 256, 0, stream>>>((const float4*)sup, dvec,
                                              (float4*)supd, c0);
    // out block
    gemm_out_k<<<dim3(64, 1, nc), 256, 0, stream>>>(B2, supd, dvec, gb, out, c0);
  }
}

// Round 2
// 1005.570 us; speedup vs baseline: 1.7087x; 1.7087x over previous
//
#include <hip/hip_runtime.h>
#include <math.h>

#define N_NODES 2048
#define NNE ((long)N_NODES * N_NODES)   // elems per channel matrix
#define NNE4 (NNE / 4)

// f16 two-term split convention: x ~= h + l * (1/2048), l stored pre-scaled
// by 2^11 so the lo part stays in f16 normal range (no subnormal flush risk).
#define LO_SCALE 2048.0f
#define LO_INV   (1.0f / 2048.0f)
// H2 is stored scaled by 2^-8 (values ~5e5 exceed f16 max 65504).
#define SH2      (1.0f / 256.0f)
#define SH2_INV  256.0f

typedef _Float16 half4_t __attribute__((ext_vector_type(4)));
typedef _Float16 half8_t __attribute__((ext_vector_type(8)));
typedef float    floatx4 __attribute__((ext_vector_type(4)));

__device__ __forceinline__ void async_cp16(const void* g, void* l) {
  // 16B per lane, LDS dest = wave-uniform base + lane*16
  __builtin_amdgcn_global_load_lds((const __attribute__((address_space(1))) void*)g,
                                   (__attribute__((address_space(3))) void*)l,
                                   16, 0, 0);
}

// ---------------- softmax of the three 4x4 weight matrices ----------------
__global__ void softmax3_k(const float* __restrict__ w1,
                           const float* __restrict__ w2,
                           const float* __restrict__ w3,
                           float* __restrict__ fw) {
  int t = threadIdx.x;
  if (t < 12) {
    const float* src = (t < 4) ? w1 : (t < 8) ? w2 : w3;
    int r = t & 3;
    float v0 = src[r * 4 + 0], v1 = src[r * 4 + 1];
    float v2 = src[r * 4 + 2], v3 = src[r * 4 + 3];
    float m = fmaxf(fmaxf(v0, v1), fmaxf(v2, v3));
    float e0 = expf(v0 - m), e1 = expf(v1 - m), e2 = expf(v2 - m), e3 = expf(v3 - m);
    float inv = 1.0f / (e0 + e1 + e2 + e3);
    fw[t * 4 + 0] = e0 * inv; fw[t * 4 + 1] = e1 * inv;
    fw[t * 4 + 2] = e2 * inv; fw[t * 4 + 3] = e3 * inv;
  }
}

// ---------------- support = X @ gcn_w  [2048,256]@[256,128] ----------------
__global__ __launch_bounds__(128)
void support_k(const float* __restrict__ X, const float* __restrict__ W,
               float* __restrict__ sup) {
  __shared__ float Xs[256];
  const int t = threadIdx.x;
  const int m = blockIdx.x;
  Xs[t]       = X[(long)m * 256 + t];
  Xs[t + 128] = X[(long)m * 256 + t + 128];
  __syncthreads();
  float acc = 0.f;
  #pragma unroll 8
  for (int k = 0; k < 256; ++k) acc = fmaf(Xs[k], W[(long)k * 128 + t], acc);
  sup[(long)m * 128 + t] = acc;
}

// ------- mix+split (row-major): O = split( sum_e fw[off+c][e] * A[e] ) ------
__global__ __launch_bounds__(256)
void mix_split_k(const float4* __restrict__ A4, const float* __restrict__ fw,
                 _Float16* __restrict__ OH, _Float16* __restrict__ OL,
                 int c0, int nc, int off) {
  long idx = (long)blockIdx.x * 256 + threadIdx.x;
  if (idx >= NNE4) return;
  float4 a0 = A4[idx];
  float4 a1 = A4[NNE4 + idx];
  float4 a2 = A4[2 * NNE4 + idx];
  float4 a3 = A4[3 * NNE4 + idx];
  for (int ci = 0; ci < nc; ++ci) {
    const float* wv = fw + off + (c0 + ci) * 4;
    float o[4];
    o[0] = wv[0] * a0.x + wv[1] * a1.x + wv[2] * a2.x + wv[3] * a3.x;
    o[1] = wv[0] * a0.y + wv[1] * a1.y + wv[2] * a2.y + wv[3] * a3.y;
    o[2] = wv[0] * a0.z + wv[1] * a1.z + wv[2] * a2.z + wv[3] * a3.z;
    o[3] = wv[0] * a0.w + wv[1] * a1.w + wv[2] * a2.w + wv[3] * a3.w;
    half4_t h, l;
    #pragma unroll
    for (int d = 0; d < 4; ++d) {
      _Float16 hh = (_Float16)o[d];
      h[d] = hh;
      l[d] = (_Float16)((o[d] - (float)hh) * LO_SCALE);
    }
    *(half4_t*)(OH + (long)ci * NNE + 4 * idx) = h;
    *(half4_t*)(OL + (long)ci * NNE + 4 * idx) = l;
  }
}

// -- mix + TRANSPOSE + split: O[c][j][i] = split( sum_e fw[off+c][e]*A[e][i][j] )
__global__ __launch_bounds__(256)
void mixT_split_k(const float* __restrict__ A, const float* __restrict__ fw,
                  _Float16* __restrict__ OH, _Float16* __restrict__ OL,
                  int c0, int nc, int off) {
  __shared__ _Float16 sh[32][33];
  __shared__ _Float16 sl[32][33];
  const int t = threadIdx.x;
  const int r0 = t >> 5, cc = t & 31;
  const int i0 = blockIdx.y * 32, j0 = blockIdx.x * 32;
  float a[4][4];
  #pragma unroll
  for (int e = 0; e < 4; ++e)
    #pragma unroll
    for (int m = 0; m < 4; ++m)
      a[e][m] = A[(long)e * NNE + (long)(i0 + r0 + 8 * m) * N_NODES + j0 + cc];

  const int jj = t >> 3, iq = (t & 7) * 4;
  for (int ci = 0; ci < nc; ++ci) {
    const float* wv = fw + off + (c0 + ci) * 4;
    #pragma unroll
    for (int m = 0; m < 4; ++m) {
      float v = wv[0] * a[0][m] + wv[1] * a[1][m] + wv[2] * a[2][m] + wv[3] * a[3][m];
      _Float16 hh = (_Float16)v;
      sh[r0 + 8 * m][cc] = hh;
      sl[r0 + 8 * m][cc] = (_Float16)((v - (float)hh) * LO_SCALE);
    }
    __syncthreads();
    half4_t oh, ol;
    #pragma unroll
    for (int d = 0; d < 4; ++d) { oh[d] = sh[iq + d][jj]; ol[d] = sl[iq + d][jj]; }
    long ob = (long)ci * NNE + (long)(j0 + jj) * N_NODES + i0 + iq;
    *(half4_t*)(OH + ob) = oh;
    *(half4_t*)(OL + ob) = ol;
    __syncthreads();
  }
}

// ------------- MFMA split-f16 GEMM (NT): C = (AH+AL/2048)(BH+BL/2048) -------
// A row-major [m][k]; B given TRANSPOSED row-major [n][k]; C written split.
// 128x128 tile / block (4 waves, 2x2), wave = 4x4 MFMA 16x16x32 tiles.
__global__ __launch_bounds__(256)
void gemm_nt_split(const _Float16* __restrict__ AH, const _Float16* __restrict__ AL,
                   const _Float16* __restrict__ BH, const _Float16* __restrict__ BL,
                   _Float16* __restrict__ CH, _Float16* __restrict__ CL,
                   float cscale) {
  __shared__ __align__(16) _Float16 sAH[128 * 32];
  __shared__ __align__(16) _Float16 sAL[128 * 32];
  __shared__ __align__(16) _Float16 sBH[128 * 32];
  __shared__ __align__(16) _Float16 sBL[128 * 32];

  const int t = threadIdx.x;
  const int lane = t & 63;
  const int w = t >> 6;
  const int wm = w >> 1, wn = w & 1;
  const int i0 = blockIdx.y * 128, j0 = blockIdx.x * 128;
  const long zo = (long)blockIdx.z * NNE;

  // staging: wave w owns one LDS tile entirely (8 x 1024B chunks)
  const _Float16* gsrc = (w == 0) ? AH : (w == 1) ? AL : (w == 2) ? BH : BL;
  _Float16* lds = (w == 0) ? sAH : (w == 1) ? sAL : (w == 2) ? sBH : sBL;
  const int rbase = (w < 2) ? i0 : j0;
  const _Float16* gp = gsrc + zo + (long)(rbase + (lane >> 2)) * N_NODES + (lane & 3) * 8;

  // fragment read positions: row = lane&15 (m or n), k = (lane>>4)*8
  const int fr = lane & 15;
  const int fk = (lane >> 4) * 8;
  const _Float16* pAH = sAH + (wm * 64 + fr) * 32 + fk;
  const _Float16* pAL = sAL + (wm * 64 + fr) * 32 + fk;
  const _Float16* pBH = sBH + (wn * 64 + fr) * 32 + fk;
  const _Float16* pBL = sBL + (wn * 64 + fr) * 32 + fk;

  floatx4 accM[4][4], accC[4][4];
  #pragma unroll
  for (int i = 0; i < 4; ++i)
    #pragma unroll
    for (int j = 0; j < 4; ++j) {
      floatx4 z = {0.f, 0.f, 0.f, 0.f};
      accM[i][j] = z; accC[i][j] = z;
    }

  for (int kt = 0; kt < N_NODES / 32; ++kt) {
    #pragma unroll
    for (int q = 0; q < 8; ++q)
      async_cp16(gp + (long)q * (16 * N_NODES), lds + q * 512);
    gp += 32;
    __syncthreads();

    half8_t ah[4], al[4], bh[4], bl[4];
    #pragma unroll
    for (int mt = 0; mt < 4; ++mt) {
      ah[mt] = *(const half8_t*)(pAH + mt * 512);
      al[mt] = *(const half8_t*)(pAL + mt * 512);
    }
    #pragma unroll
    for (int nt = 0; nt < 4; ++nt) {
      bh[nt] = *(const half8_t*)(pBH + nt * 512);
      bl[nt] = *(const half8_t*)(pBL + nt * 512);
    }
    #pragma unroll
    for (int mt = 0; mt < 4; ++mt)
      #pragma unroll
      for (int nt = 0; nt < 4; ++nt) {
        accM[mt][nt] = __builtin_amdgcn_mfma_f32_16x16x32_f16(ah[mt], bh[nt], accM[mt][nt], 0, 0, 0);
        accC[mt][nt] = __builtin_amdgcn_mfma_f32_16x16x32_f16(al[mt], bh[nt], accC[mt][nt], 0, 0, 0);
        accC[mt][nt] = __builtin_amdgcn_mfma_f32_16x16x32_f16(ah[mt], bl[nt], accC[mt][nt], 0, 0, 0);
      }
    __syncthreads();
  }

  // epilogue: C/D layout col = lane&15, row = (lane>>4)*4 + reg
  const int er = (lane >> 4) * 4;
  const int ec = lane & 15;
  #pragma unroll
  for (int mt = 0; mt < 4; ++mt)
    #pragma unroll
    for (int nt = 0; nt < 4; ++nt) {
      floatx4 v = accM[mt][nt] + accC[mt][nt] * LO_INV;
      const int jb = j0 + wn * 64 + nt * 16 + ec;
      #pragma unroll
      for (int r = 0; r < 4; ++r) {
        float x = v[r] * cscale;
        _Float16 h = (_Float16)x;
        _Float16 lo = (_Float16)((x - (float)h) * LO_SCALE);
        long o = zo + (long)(i0 + wm * 64 + mt * 16 + er + r) * N_NODES + jb;
        CH[o] = h;
        CL[o] = lo;
      }
    }
}

// ------- d = 1/sqrt(1 + SH2_INV * rowsum(H2s)), H2s in split form ----------
__global__ __launch_bounds__(256)
void rowsum_split_k(const _Float16* __restrict__ H2H, const _Float16* __restrict__ H2L,
                    float* __restrict__ dvec, int c0) {
  const int t = threadIdx.x;
  const long rb = (long)blockIdx.y * NNE + (long)blockIdx.x * N_NODES;
  half8_t h = *(const half8_t*)(H2H + rb + t * 8);
  half8_t l = *(const half8_t*)(H2L + rb + t * 8);
  float s = 0.f;
  #pragma unroll
  for (int d = 0; d < 8; ++d) s += (float)h[d] + (float)l[d] * LO_INV;
  for (int off = 32; off > 0; off >>= 1) s += __shfl_down(s, off, 64);
  __shared__ float red[4];
  if ((t & 63) == 0) red[t >> 6] = s;
  __syncthreads();
  if (t == 0) {
    float deg = 1.0f + SH2_INV * ((red[0] + red[1]) + (red[2] + red[3]));
    dvec[(long)(c0 + blockIdx.y) * N_NODES + blockIdx.x] = 1.0f / sqrtf(deg);
  }
}

// ---------------- supd[c][m][f] = d[c][m] * support[m][f] -------------------
__global__ __launch_bounds__(256)
void supd_k(const float4* __restrict__ sup4, const float* __restrict__ dvec,
            float4* __restrict__ out4, int c0) {
  const int c = c0 + blockIdx.y;
  const int idx = blockIdx.x * 256 + threadIdx.x;
  const int m = idx >> 5;
  float dm = dvec[(long)c * N_NODES + m];
  float4 v = sup4[idx];
  v.x *= dm; v.y *= dm; v.z *= dm; v.w *= dm;
  out4[(long)c * (N_NODES * 32) + idx] = v;
}

// --- out[:, c*128:(c+1)*128] = relu(dn*(SH2_INV*(H2s@supd) + supd_n) + b) ---
__global__ __launch_bounds__(256)
void gemm_out_k(const _Float16* __restrict__ H2H, const _Float16* __restrict__ H2L,
                const float* __restrict__ supd, const float* __restrict__ dvec,
                const float* __restrict__ bias, float* __restrict__ out, int c0) {
  const int t = threadIdx.x;
  const int c = c0 + blockIdx.z;
  const _Float16* A2H = H2H + (long)blockIdx.z * NNE;
  const _Float16* A2L = H2L + (long)blockIdx.z * NNE;
  const float* Bsup = supd + (long)c * N_NODES * 128;
  const float* dv   = dvec + (long)c * N_NODES;
  const int i0 = blockIdx.x * 32;

  __shared__ float As[32][36];
  __shared__ float Bs[32][128];

  const int arow = t >> 3;
  const int akq  = (t & 7) << 2;
  const int brow = t >> 5;
  const int bjq  = (t & 31) << 2;
  const int tx = t & 31, ty = t >> 5;

  float acc[4][4];
  #pragma unroll
  for (int r = 0; r < 4; ++r)
    #pragma unroll
    for (int s = 0; s < 4; ++s) acc[r][s] = 0.f;

  const int nk = N_NODES / 32;
  for (int kt = 0; kt < nk; ++kt) {
    const int k0 = kt * 32;
    __syncthreads();
    half4_t hh = *(const half4_t*)(A2H + (long)(i0 + arow) * N_NODES + k0 + akq);
    half4_t ll = *(const half4_t*)(A2L + (long)(i0 + arow) * N_NODES + k0 + akq);
    #pragma unroll
    for (int d = 0; d < 4; ++d)
      As[akq + d][arow] = (float)hh[d] + (float)ll[d] * LO_INV;
    #pragma unroll
    for (int m = 0; m < 4; ++m)
      *(float4*)&Bs[brow + 8 * m][bjq] =
          *(const float4*)(Bsup + (long)(k0 + brow + 8 * m) * 128 + bjq);
    __syncthreads();
    #pragma unroll
    for (int k = 0; k < 32; ++k) {
      float av[4], bv[4];
      *(float4*)&av[0] = *(const float4*)&As[k][ty * 4];
      *(float4*)&bv[0] = *(const float4*)&Bs[k][tx * 4];
      #pragma unroll
      for (int r = 0; r < 4; ++r)
        #pragma unroll
        for (int s = 0; s < 4; ++s)
          acc[r][s] = fmaf(av[r], bv[s], acc[r][s]);
    }
  }
  #pragma unroll
  for (int r = 0; r < 4; ++r) {
    const int i = i0 + ty * 4 + r;
    const float dn = dv[i];
    float4 o;
    o.x = fmaxf(dn * (acc[r][0] * SH2_INV + Bsup[(long)i * 128 + tx * 4 + 0]) + bias[tx * 4 + 0], 0.f);
    o.y = fmaxf(dn * (acc[r][1] * SH2_INV + Bsup[(long)i * 128 + tx * 4 + 1]) + bias[tx * 4 + 1], 0.f);
    o.z = fmaxf(dn * (acc[r][2] * SH2_INV + Bsup[(long)i * 128 + tx * 4 + 2]) + bias[tx * 4 + 2], 0.f);
    o.w = fmaxf(dn * (acc[r][3] * SH2_INV + Bsup[(long)i * 128 + tx * 4 + 3]) + bias[tx * 4 + 3], 0.f);
    *(float4*)(out + (long)i * 512 + c * 128 + tx * 4) = o;
  }
}

extern "C" void kernel_launch(void* const* d_in, const int* in_sizes, int n_in,
                              void* d_out, int out_size, void* d_ws, size_t ws_size,
                              hipStream_t stream) {
  const float* A  = (const float*)d_in[0];
  const float* X  = (const float*)d_in[1];
  const float* w1 = (const float*)d_in[2];
  const float* w2 = (const float*)d_in[3];
  const float* w3 = (const float*)d_in[4];
  const float* gw = (const float*)d_in[5];
  const float* gb = (const float*)d_in[6];
  float* out = (float*)d_out;

  float* ws   = (float*)d_ws;
  float* fw   = ws;                              // 64 floats
  float* dvec = ws + 64;                         // 4*2048
  float* sup  = dvec + 4 * N_NODES;              // 2048*128
  float* supd = sup + (long)N_NODES * 128;       // 4*2048*128
  _Float16* arena = (_Float16*)(supd + (long)4 * N_NODES * 128);

  const long base_bytes = (long)(64 + 4 * N_NODES + (long)N_NODES * 128 +
                                 (long)4 * N_NODES * 128) * 4;
  int nc = 1;
  if ((long)ws_size >= base_bytes + 12L * 4 * NNE) nc = 4;       // 3 split-pairs
  else if ((long)ws_size >= base_bytes + 12L * 2 * NNE) nc = 2;

  _Float16* P1H = arena;
  _Float16* P1L = P1H + (long)nc * NNE;
  _Float16* P2H = P1L + (long)nc * NNE;
  _Float16* P2L = P2H + (long)nc * NNE;
  _Float16* P3H = P2L + (long)nc * NNE;
  _Float16* P3L = P3H + (long)nc * NNE;

  softmax3_k<<<1, 64, 0, stream>>>(w1, w2, w3, fw);
  support_k<<<N_NODES, 128, 0, stream>>>(X, gw, sup);

  for (int c0 = 0; c0 < 4; c0 += nc) {
    // Ha (row-major split) -> P1 ; HbT (transposed split) -> P2
    mix_split_k<<<4096, 256, 0, stream>>>((const float4*)A, fw, P1H, P1L, c0, nc, 0);
    mixT_split_k<<<dim3(64, 64), 256, 0, stream>>>(A, fw, P2H, P2L, c0, nc, 16);
    // H1 = Ha @ Hb -> P3 (split, unscaled; |H1| < 2048 fits f16)
    gemm_nt_split<<<dim3(16, 16, nc), 256, 0, stream>>>(P1H, P1L, P2H, P2L, P3H, P3L, 1.0f);
    // HcT -> P1 (Ha no longer needed)
    mixT_split_k<<<dim3(64, 64), 256, 0, stream>>>(A, fw, P1H, P1L, c0, nc, 32);
    // H2s = (H1 @ Hc) * 2^-8 -> P2 (HbT no longer needed)
    gemm_nt_split<<<dim3(16, 16, nc), 256, 0, stream>>>(P3H, P3L, P1H, P1L, P2H, P2L, SH2);
    rowsum_split_k<<<dim3(N_NODES, nc), 256, 0, stream>>>(P2H, P2L, dvec, c0);
    supd_k<<<dim3(256, nc), 256, 0, stream>>>((const float4*)sup, dvec, (float4*)supd, c0);
    gemm_out_k<<<dim3(64, 1, nc), 256, 0, stream>>>(P2H, P2L, supd, dvec, gb, out, c0);
  }
}

// Round 3
// 682.382 us; speedup vs baseline: 2.5179x; 1.4736x over previous
//
#include <hip/hip_runtime.h>
#include <math.h>

#define N_NODES 2048
#define NNE ((long)N_NODES * N_NODES)   // elems per channel matrix
#define NNE4 (NNE / 4)

// f16 two-term split: x ~= h + l, where h = f16(x) and l = f16(x - h) is the
// TRUE residual (magnitude ~2^-11 * |x|). Power-of-2 scales are exact, and
// subnormal flushing of tiny residuals only loses error that is already
// ~2^-11 relative to the element — harmless. This lets all 3 MFMA products
// (h*h, l*h, h*l) accumulate into ONE fp32 accumulator (halves AGPR use).
// H2 is stored scaled by 2^-8 (values ~5e5 exceed f16 max 65504).
#define SH2      (1.0f / 256.0f)
#define SH2_INV  256.0f

typedef _Float16 half4_t __attribute__((ext_vector_type(4)));
typedef _Float16 half8_t __attribute__((ext_vector_type(8)));
typedef float    floatx4 __attribute__((ext_vector_type(4)));

__device__ __forceinline__ void async_cp16(const void* g, void* l) {
  __builtin_amdgcn_global_load_lds((const __attribute__((address_space(1))) void*)g,
                                   (__attribute__((address_space(3))) void*)l,
                                   16, 0, 0);
}

// ---------------- softmax of the three 4x4 weight matrices ----------------
__global__ void softmax3_k(const float* __restrict__ w1,
                           const float* __restrict__ w2,
                           const float* __restrict__ w3,
                           float* __restrict__ fw) {
  int t = threadIdx.x;
  if (t < 12) {
    const float* src = (t < 4) ? w1 : (t < 8) ? w2 : w3;
    int r = t & 3;
    float v0 = src[r * 4 + 0], v1 = src[r * 4 + 1];
    float v2 = src[r * 4 + 2], v3 = src[r * 4 + 3];
    float m = fmaxf(fmaxf(v0, v1), fmaxf(v2, v3));
    float e0 = expf(v0 - m), e1 = expf(v1 - m), e2 = expf(v2 - m), e3 = expf(v3 - m);
    float inv = 1.0f / (e0 + e1 + e2 + e3);
    fw[t * 4 + 0] = e0 * inv; fw[t * 4 + 1] = e1 * inv;
    fw[t * 4 + 2] = e2 * inv; fw[t * 4 + 3] = e3 * inv;
  }
}

// ---------------- support = X @ gcn_w  [2048,256]@[256,128] ----------------
__global__ __launch_bounds__(128)
void support_k(const float* __restrict__ X, const float* __restrict__ W,
               float* __restrict__ sup) {
  __shared__ float Xs[256];
  const int t = threadIdx.x;
  const int m = blockIdx.x;
  Xs[t]       = X[(long)m * 256 + t];
  Xs[t + 128] = X[(long)m * 256 + t + 128];
  __syncthreads();
  float acc = 0.f;
  #pragma unroll 8
  for (int k = 0; k < 256; ++k) acc = fmaf(Xs[k], W[(long)k * 128 + t], acc);
  sup[(long)m * 128 + t] = acc;
}

// ------- mix+split (row-major): O = split( sum_e fw[off+c][e] * A[e] ) ------
__global__ __launch_bounds__(256)
void mix_split_k(const float4* __restrict__ A4, const float* __restrict__ fw,
                 _Float16* __restrict__ OH, _Float16* __restrict__ OL,
                 int c0, int nc, int off) {
  long idx = (long)blockIdx.x * 256 + threadIdx.x;
  if (idx >= NNE4) return;
  float4 a0 = A4[idx];
  float4 a1 = A4[NNE4 + idx];
  float4 a2 = A4[2 * NNE4 + idx];
  float4 a3 = A4[3 * NNE4 + idx];
  for (int ci = 0; ci < nc; ++ci) {
    const float* wv = fw + off + (c0 + ci) * 4;
    float o[4];
    o[0] = wv[0] * a0.x + wv[1] * a1.x + wv[2] * a2.x + wv[3] * a3.x;
    o[1] = wv[0] * a0.y + wv[1] * a1.y + wv[2] * a2.y + wv[3] * a3.y;
    o[2] = wv[0] * a0.z + wv[1] * a1.z + wv[2] * a2.z + wv[3] * a3.z;
    o[3] = wv[0] * a0.w + wv[1] * a1.w + wv[2] * a2.w + wv[3] * a3.w;
    half4_t h, l;
    #pragma unroll
    for (int d = 0; d < 4; ++d) {
      _Float16 hh = (_Float16)o[d];
      h[d] = hh;
      l[d] = (_Float16)(o[d] - (float)hh);   // true residual
    }
    *(half4_t*)(OH + (long)ci * NNE + 4 * idx) = h;
    *(half4_t*)(OL + (long)ci * NNE + 4 * idx) = l;
  }
}

// -- mix + TRANSPOSE + split: O[c][j][i] = split( sum_e fw[off+c][e]*A[e][i][j] )
__global__ __launch_bounds__(256)
void mixT_split_k(const float* __restrict__ A, const float* __restrict__ fw,
                  _Float16* __restrict__ OH, _Float16* __restrict__ OL,
                  int c0, int nc, int off) {
  __shared__ _Float16 sh[32][33];
  __shared__ _Float16 sl[32][33];
  const int t = threadIdx.x;
  const int r0 = t >> 5, cc = t & 31;
  const int i0 = blockIdx.y * 32, j0 = blockIdx.x * 32;
  float a[4][4];
  #pragma unroll
  for (int e = 0; e < 4; ++e)
    #pragma unroll
    for (int m = 0; m < 4; ++m)
      a[e][m] = A[(long)e * NNE + (long)(i0 + r0 + 8 * m) * N_NODES + j0 + cc];

  const int jj = t >> 3, iq = (t & 7) * 4;
  for (int ci = 0; ci < nc; ++ci) {
    const float* wv = fw + off + (c0 + ci) * 4;
    #pragma unroll
    for (int m = 0; m < 4; ++m) {
      float v = wv[0] * a[0][m] + wv[1] * a[1][m] + wv[2] * a[2][m] + wv[3] * a[3][m];
      _Float16 hh = (_Float16)v;
      sh[r0 + 8 * m][cc] = hh;
      sl[r0 + 8 * m][cc] = (_Float16)(v - (float)hh);
    }
    __syncthreads();
    half4_t oh, ol;
    #pragma unroll
    for (int d = 0; d < 4; ++d) { oh[d] = sh[iq + d][jj]; ol[d] = sl[iq + d][jj]; }
    long ob = (long)ci * NNE + (long)(j0 + jj) * N_NODES + i0 + iq;
    *(half4_t*)(OH + ob) = oh;
    *(half4_t*)(OL + ob) = ol;
    __syncthreads();
  }
}

// ------------- MFMA split-f16 GEMM (NT): C = (AH+AL)(BH+BL) ----------------
// A row-major [m][k]; B TRANSPOSED row-major [n][k]; C written split (x cscale).
// Single accumulator per 16x16 tile (3 chained MFMAs); 2 waves/SIMD target.
// If deg != nullptr, also atomically accumulates rowsum(C) into deg[z][row].
__global__ __launch_bounds__(256, 2)
void gemm_nt_split(const _Float16* __restrict__ AH, const _Float16* __restrict__ AL,
                   const _Float16* __restrict__ BH, const _Float16* __restrict__ BL,
                   _Float16* __restrict__ CH, _Float16* __restrict__ CL,
                   float cscale, float* __restrict__ deg) {
  __shared__ __align__(16) _Float16 sAH[128 * 32];
  __shared__ __align__(16) _Float16 sAL[128 * 32];
  __shared__ __align__(16) _Float16 sBH[128 * 32];
  __shared__ __align__(16) _Float16 sBL[128 * 32];

  const int t = threadIdx.x;
  const int lane = t & 63;
  const int w = t >> 6;
  const int wm = w >> 1, wn = w & 1;
  const int i0 = blockIdx.y * 128, j0 = blockIdx.x * 128;
  const long zo = (long)blockIdx.z * NNE;

  const _Float16* gsrc = (w == 0) ? AH : (w == 1) ? AL : (w == 2) ? BH : BL;
  _Float16* lds = (w == 0) ? sAH : (w == 1) ? sAL : (w == 2) ? sBH : sBL;
  const int rbase = (w < 2) ? i0 : j0;
  const _Float16* gp = gsrc + zo + (long)(rbase + (lane >> 2)) * N_NODES + (lane & 3) * 8;

  const int fr = lane & 15;
  const int fk = (lane >> 4) * 8;
  const _Float16* pAH = sAH + (wm * 64 + fr) * 32 + fk;
  const _Float16* pAL = sAL + (wm * 64 + fr) * 32 + fk;
  const _Float16* pBH = sBH + (wn * 64 + fr) * 32 + fk;
  const _Float16* pBL = sBL + (wn * 64 + fr) * 32 + fk;

  floatx4 acc[4][4];
  #pragma unroll
  for (int i = 0; i < 4; ++i)
    #pragma unroll
    for (int j = 0; j < 4; ++j) {
      floatx4 z = {0.f, 0.f, 0.f, 0.f};
      acc[i][j] = z;
    }

  for (int kt = 0; kt < N_NODES / 32; ++kt) {
    #pragma unroll
    for (int q = 0; q < 8; ++q)
      async_cp16(gp + (long)q * (16 * N_NODES), lds + q * 512);
    gp += 32;
    __syncthreads();

    half8_t ah[4], al[4], bh[4], bl[4];
    #pragma unroll
    for (int mt = 0; mt < 4; ++mt) {
      ah[mt] = *(const half8_t*)(pAH + mt * 512);
      al[mt] = *(const half8_t*)(pAL + mt * 512);
    }
    #pragma unroll
    for (int nt = 0; nt < 4; ++nt) {
      bh[nt] = *(const half8_t*)(pBH + nt * 512);
      bl[nt] = *(const half8_t*)(pBL + nt * 512);
    }
    #pragma unroll
    for (int mt = 0; mt < 4; ++mt)
      #pragma unroll
      for (int nt = 0; nt < 4; ++nt) {
        acc[mt][nt] = __builtin_amdgcn_mfma_f32_16x16x32_f16(ah[mt], bh[nt], acc[mt][nt], 0, 0, 0);
        acc[mt][nt] = __builtin_amdgcn_mfma_f32_16x16x32_f16(al[mt], bh[nt], acc[mt][nt], 0, 0, 0);
        acc[mt][nt] = __builtin_amdgcn_mfma_f32_16x16x32_f16(ah[mt], bl[nt], acc[mt][nt], 0, 0, 0);
      }
    __syncthreads();
  }

  // epilogue: C/D layout col = lane&15, row = (lane>>4)*4 + reg
  const int er = (lane >> 4) * 4;
  const int ec = lane & 15;
  #pragma unroll
  for (int mt = 0; mt < 4; ++mt) {
    float s[4] = {0.f, 0.f, 0.f, 0.f};
    #pragma unroll
    for (int nt = 0; nt < 4; ++nt) {
      const int jb = j0 + wn * 64 + nt * 16 + ec;
      #pragma unroll
      for (int r = 0; r < 4; ++r) {
        float x = acc[mt][nt][r] * cscale;
        s[r] += x;
        _Float16 h = (_Float16)x;
        long o = zo + (long)(i0 + wm * 64 + mt * 16 + er + r) * N_NODES + jb;
        CH[o] = h;
        CL[o] = (_Float16)(x - (float)h);
      }
    }
    if (deg) {
      #pragma unroll
      for (int r = 0; r < 4; ++r) {
        s[r] += __shfl_xor(s[r], 1, 64);
        s[r] += __shfl_xor(s[r], 2, 64);
        s[r] += __shfl_xor(s[r], 4, 64);
        s[r] += __shfl_xor(s[r], 8, 64);
      }
      if (ec == 0) {
        float* dp = deg + (long)blockIdx.z * N_NODES + i0 + wm * 64 + mt * 16 + er;
        #pragma unroll
        for (int r = 0; r < 4; ++r) atomicAdd(dp + r, s[r]);
      }
    }
  }
}

// -- supd[c][m][f] = d[c][m]*support[m][f], d = 1/sqrt(1+256*deg); save dvec --
__global__ __launch_bounds__(256)
void supd_k(const float4* __restrict__ sup4, const float* __restrict__ deg,
            float* __restrict__ dvec, float4* __restrict__ out4, int c0) {
  const int c = c0 + blockIdx.y;
  const int idx = blockIdx.x * 256 + threadIdx.x;
  const int m = idx >> 5;
  float dm = 1.0f / sqrtf(1.0f + SH2_INV * deg[(long)c * N_NODES + m]);
  if ((idx & 31) == 0) dvec[(long)c * N_NODES + m] = dm;
  float4 v = sup4[idx];
  v.x *= dm; v.y *= dm; v.z *= dm; v.w *= dm;
  out4[(long)c * (N_NODES * 32) + idx] = v;
}

// --- out[:, c*128:(c+1)*128] = relu(dn*(SH2_INV*(H2s@supd) + supd_n) + b) ---
__global__ __launch_bounds__(256)
void gemm_out_k(const _Float16* __restrict__ H2H, const _Float16* __restrict__ H2L,
                const float* __restrict__ supd, const float* __restrict__ dvec,
                const float* __restrict__ bias, float* __restrict__ out, int c0) {
  const int t = threadIdx.x;
  const int c = c0 + blockIdx.z;
  const _Float16* A2H = H2H + (long)blockIdx.z * NNE;
  const _Float16* A2L = H2L + (long)blockIdx.z * NNE;
  const float* Bsup = supd + (long)c * N_NODES * 128;
  const float* dv   = dvec + (long)c * N_NODES;
  const int i0 = blockIdx.x * 32;

  __shared__ float As[32][36];
  __shared__ float Bs[32][128];

  const int arow = t >> 3;
  const int akq  = (t & 7) << 2;
  const int brow = t >> 5;
  const int bjq  = (t & 31) << 2;
  const int tx = t & 31, ty = t >> 5;

  float acc[4][4];
  #pragma unroll
  for (int r = 0; r < 4; ++r)
    #pragma unroll
    for (int s = 0; s < 4; ++s) acc[r][s] = 0.f;

  const int nk = N_NODES / 32;
  for (int kt = 0; kt < nk; ++kt) {
    const int k0 = kt * 32;
    __syncthreads();
    half4_t hh = *(const half4_t*)(A2H + (long)(i0 + arow) * N_NODES + k0 + akq);
    half4_t ll = *(const half4_t*)(A2L + (long)(i0 + arow) * N_NODES + k0 + akq);
    #pragma unroll
    for (int d = 0; d < 4; ++d)
      As[akq + d][arow] = (float)hh[d] + (float)ll[d];
    #pragma unroll
    for (int m = 0; m < 4; ++m)
      *(float4*)&Bs[brow + 8 * m][bjq] =
          *(const float4*)(Bsup + (long)(k0 + brow + 8 * m) * 128 + bjq);
    __syncthreads();
    #pragma unroll
    for (int k = 0; k < 32; ++k) {
      float av[4], bv[4];
      *(float4*)&av[0] = *(const float4*)&As[k][ty * 4];
      *(float4*)&bv[0] = *(const float4*)&Bs[k][tx * 4];
      #pragma unroll
      for (int r = 0; r < 4; ++r)
        #pragma unroll
        for (int s = 0; s < 4; ++s)
          acc[r][s] = fmaf(av[r], bv[s], acc[r][s]);
    }
  }
  #pragma unroll
  for (int r = 0; r < 4; ++r) {
    const int i = i0 + ty * 4 + r;
    const float dn = dv[i];
    float4 o;
    o.x = fmaxf(dn * (acc[r][0] * SH2_INV + Bsup[(long)i * 128 + tx * 4 + 0]) + bias[tx * 4 + 0], 0.f);
    o.y = fmaxf(dn * (acc[r][1] * SH2_INV + Bsup[(long)i * 128 + tx * 4 + 1]) + bias[tx * 4 + 1], 0.f);
    o.z = fmaxf(dn * (acc[r][2] * SH2_INV + Bsup[(long)i * 128 + tx * 4 + 2]) + bias[tx * 4 + 2], 0.f);
    o.w = fmaxf(dn * (acc[r][3] * SH2_INV + Bsup[(long)i * 128 + tx * 4 + 3]) + bias[tx * 4 + 3], 0.f);
    *(float4*)(out + (long)i * 512 + c * 128 + tx * 4) = o;
  }
}

extern "C" void kernel_launch(void* const* d_in, const int* in_sizes, int n_in,
                              void* d_out, int out_size, void* d_ws, size_t ws_size,
                              hipStream_t stream) {
  const float* A  = (const float*)d_in[0];
  const float* X  = (const float*)d_in[1];
  const float* w1 = (const float*)d_in[2];
  const float* w2 = (const float*)d_in[3];
  const float* w3 = (const float*)d_in[4];
  const float* gw = (const float*)d_in[5];
  const float* gb = (const float*)d_in[6];
  float* out = (float*)d_out;

  float* ws   = (float*)d_ws;
  float* fw   = ws;                              // 64 floats
  float* dvec = ws + 64;                         // 4*2048
  float* deg  = dvec + 4 * N_NODES;              // 4*2048
  float* sup  = deg + 4 * N_NODES;               // 2048*128
  float* supd = sup + (long)N_NODES * 128;       // 4*2048*128
  _Float16* arena = (_Float16*)(supd + (long)4 * N_NODES * 128);

  const long base_bytes = (long)(64 + 8 * N_NODES + (long)N_NODES * 128 +
                                 (long)4 * N_NODES * 128) * 4;
  int nc = 1;
  if ((long)ws_size >= base_bytes + 12L * 4 * NNE) nc = 4;
  else if ((long)ws_size >= base_bytes + 12L * 2 * NNE) nc = 2;

  _Float16* P1H = arena;
  _Float16* P1L = P1H + (long)nc * NNE;
  _Float16* P2H = P1L + (long)nc * NNE;
  _Float16* P2L = P2H + (long)nc * NNE;
  _Float16* P3H = P2L + (long)nc * NNE;
  _Float16* P3L = P3H + (long)nc * NNE;

  softmax3_k<<<1, 64, 0, stream>>>(w1, w2, w3, fw);
  support_k<<<N_NODES, 128, 0, stream>>>(X, gw, sup);
  hipMemsetAsync(deg, 0, 4 * N_NODES * sizeof(float), stream);

  for (int c0 = 0; c0 < 4; c0 += nc) {
    // Ha (row-major split) -> P1 ; HbT (transposed split) -> P2
    mix_split_k<<<4096, 256, 0, stream>>>((const float4*)A, fw, P1H, P1L, c0, nc, 0);
    mixT_split_k<<<dim3(64, 64), 256, 0, stream>>>(A, fw, P2H, P2L, c0, nc, 16);
    // H1 = Ha @ Hb -> P3 (|H1| < 2048 fits f16)
    gemm_nt_split<<<dim3(16, 16, nc), 256, 0, stream>>>(P1H, P1L, P2H, P2L, P3H, P3L,
                                                        1.0f, nullptr);
    // HcT -> P1
    mixT_split_k<<<dim3(64, 64), 256, 0, stream>>>(A, fw, P1H, P1L, c0, nc, 32);
    // H2s = (H1 @ Hc) * 2^-8 -> P2, fused rowsum -> deg
    gemm_nt_split<<<dim3(16, 16, nc), 256, 0, stream>>>(P3H, P3L, P1H, P1L, P2H, P2L,
                                                        SH2, deg + (long)c0 * N_NODES);
    // supd = d * support (d from deg), save dvec
    supd_k<<<dim3(256, nc), 256, 0, stream>>>((const float4*)sup, deg, dvec,
                                              (float4*)supd, c0);
    gemm_out_k<<<dim3(64, 1, nc), 256, 0, stream>>>(P2H, P2L, supd, dvec, gb, out, c0);
  }
}

// Round 4
// 670.980 us; speedup vs baseline: 2.5607x; 1.0170x over previous
//
#include <hip/hip_runtime.h>
#include <math.h>

#define N_NODES 2048
#define NNE ((long)N_NODES * N_NODES)   // elems per channel matrix
#define NNE4 (NNE / 4)

// f16 two-term split: x ~= h + l, h = f16(x), l = f16(x - h) true residual.
// Three MFMA products (hh, lh, hl) into ONE fp32 accumulator; dropped l*l
// term is ~2^-22 relative. H2 stored scaled by 2^-8 (exceeds f16 max).
#define SH2      (1.0f / 256.0f)
#define SH2_INV  256.0f

typedef _Float16 half4_t __attribute__((ext_vector_type(4)));
typedef _Float16 half8_t __attribute__((ext_vector_type(8)));
typedef float    floatx4 __attribute__((ext_vector_type(4)));

__device__ __forceinline__ void async_cp16(const void* g, void* l) {
  // HW computes LDS dest = wave-uniform base + lane*16
  __builtin_amdgcn_global_load_lds((const __attribute__((address_space(1))) void*)g,
                                   (__attribute__((address_space(3))) void*)l,
                                   16, 0, 0);
}

// ---------------- softmax of the three 4x4 weight matrices ----------------
__global__ void softmax3_k(const float* __restrict__ w1,
                           const float* __restrict__ w2,
                           const float* __restrict__ w3,
                           float* __restrict__ fw) {
  int t = threadIdx.x;
  if (t < 12) {
    const float* src = (t < 4) ? w1 : (t < 8) ? w2 : w3;
    int r = t & 3;
    float v0 = src[r * 4 + 0], v1 = src[r * 4 + 1];
    float v2 = src[r * 4 + 2], v3 = src[r * 4 + 3];
    float m = fmaxf(fmaxf(v0, v1), fmaxf(v2, v3));
    float e0 = expf(v0 - m), e1 = expf(v1 - m), e2 = expf(v2 - m), e3 = expf(v3 - m);
    float inv = 1.0f / (e0 + e1 + e2 + e3);
    fw[t * 4 + 0] = e0 * inv; fw[t * 4 + 1] = e1 * inv;
    fw[t * 4 + 2] = e2 * inv; fw[t * 4 + 3] = e3 * inv;
  }
}

// ---------------- support = X @ gcn_w  [2048,256]@[256,128] ----------------
__global__ __launch_bounds__(128)
void support_k(const float* __restrict__ X, const float* __restrict__ W,
               float* __restrict__ sup) {
  __shared__ float Xs[256];
  const int t = threadIdx.x;
  const int m = blockIdx.x;
  Xs[t]       = X[(long)m * 256 + t];
  Xs[t + 128] = X[(long)m * 256 + t + 128];
  __syncthreads();
  float acc = 0.f;
  #pragma unroll 8
  for (int k = 0; k < 256; ++k) acc = fmaf(Xs[k], W[(long)k * 128 + t], acc);
  sup[(long)m * 128 + t] = acc;
}

// -- fused: Ha (row-major split) AND HbT (transposed split) in one A pass ---
__global__ __launch_bounds__(256)
void mixAB_k(const float* __restrict__ A, const float* __restrict__ fw,
             _Float16* __restrict__ HaH, _Float16* __restrict__ HaL,
             _Float16* __restrict__ HbH, _Float16* __restrict__ HbL,
             int c0, int nc) {
  __shared__ _Float16 s1h[32][33], s1l[32][33];
  __shared__ _Float16 s2h[32][33], s2l[32][33];
  const int t = threadIdx.x;
  const int r0 = t >> 5, cc = t & 31;
  const int i0 = blockIdx.y * 32, j0 = blockIdx.x * 32;
  float a[4][4];
  #pragma unroll
  for (int e = 0; e < 4; ++e)
    #pragma unroll
    for (int m = 0; m < 4; ++m)
      a[e][m] = A[(long)e * NNE + (long)(i0 + r0 + 8 * m) * N_NODES + j0 + cc];

  const int rr = t >> 3, cq = (t & 7) * 4;
  for (int ci = 0; ci < nc; ++ci) {
    const float* wa = fw + (c0 + ci) * 4;
    const float* wb = fw + 16 + (c0 + ci) * 4;
    #pragma unroll
    for (int m = 0; m < 4; ++m) {
      float v1 = wa[0] * a[0][m] + wa[1] * a[1][m] + wa[2] * a[2][m] + wa[3] * a[3][m];
      float v2 = wb[0] * a[0][m] + wb[1] * a[1][m] + wb[2] * a[2][m] + wb[3] * a[3][m];
      _Float16 h1 = (_Float16)v1;
      s1h[r0 + 8 * m][cc] = h1;
      s1l[r0 + 8 * m][cc] = (_Float16)(v1 - (float)h1);
      _Float16 h2 = (_Float16)v2;
      s2h[r0 + 8 * m][cc] = h2;
      s2l[r0 + 8 * m][cc] = (_Float16)(v2 - (float)h2);
    }
    __syncthreads();
    // Ha row-major
    half4_t oh, ol;
    #pragma unroll
    for (int d = 0; d < 4; ++d) { oh[d] = s1h[rr][cq + d]; ol[d] = s1l[rr][cq + d]; }
    long o1 = (long)ci * NNE + (long)(i0 + rr) * N_NODES + j0 + cq;
    *(half4_t*)(HaH + o1) = oh;
    *(half4_t*)(HaL + o1) = ol;
    // HbT transposed
    #pragma unroll
    for (int d = 0; d < 4; ++d) { oh[d] = s2h[cq + d][rr]; ol[d] = s2l[cq + d][rr]; }
    long o2 = (long)ci * NNE + (long)(j0 + rr) * N_NODES + i0 + cq;
    *(half4_t*)(HbH + o2) = oh;
    *(half4_t*)(HbL + o2) = ol;
    __syncthreads();
  }
}

// -- mix + TRANSPOSE + split: O[c][j][i] = split( sum_e fw[off+c][e]*A[e][i][j] )
__global__ __launch_bounds__(256)
void mixT_split_k(const float* __restrict__ A, const float* __restrict__ fw,
                  _Float16* __restrict__ OH, _Float16* __restrict__ OL,
                  int c0, int nc, int off) {
  __shared__ _Float16 sh[32][33];
  __shared__ _Float16 sl[32][33];
  const int t = threadIdx.x;
  const int r0 = t >> 5, cc = t & 31;
  const int i0 = blockIdx.y * 32, j0 = blockIdx.x * 32;
  float a[4][4];
  #pragma unroll
  for (int e = 0; e < 4; ++e)
    #pragma unroll
    for (int m = 0; m < 4; ++m)
      a[e][m] = A[(long)e * NNE + (long)(i0 + r0 + 8 * m) * N_NODES + j0 + cc];

  const int jj = t >> 3, iq = (t & 7) * 4;
  for (int ci = 0; ci < nc; ++ci) {
    const float* wv = fw + off + (c0 + ci) * 4;
    #pragma unroll
    for (int m = 0; m < 4; ++m) {
      float v = wv[0] * a[0][m] + wv[1] * a[1][m] + wv[2] * a[2][m] + wv[3] * a[3][m];
      _Float16 hh = (_Float16)v;
      sh[r0 + 8 * m][cc] = hh;
      sl[r0 + 8 * m][cc] = (_Float16)(v - (float)hh);
    }
    __syncthreads();
    half4_t oh, ol;
    #pragma unroll
    for (int d = 0; d < 4; ++d) { oh[d] = sh[iq + d][jj]; ol[d] = sl[iq + d][jj]; }
    long ob = (long)ci * NNE + (long)(j0 + jj) * N_NODES + i0 + iq;
    *(half4_t*)(OH + ob) = oh;
    *(half4_t*)(OL + ob) = ol;
    __syncthreads();
  }
}

// ------------- MFMA split-f16 GEMM (NT): C = (AH+AL)(BH+BL) ----------------
// Double-buffered LDS (2x32KB) + XOR-swizzled 16B chunks (conflict-free).
// A row-major [m][k]; B TRANSPOSED row-major [n][k]; C written split (x cscale).
// If deg != nullptr, also accumulates rowsum(C) into deg[z][row].
__global__ __launch_bounds__(256, 2)
void gemm_nt_split(const _Float16* __restrict__ AH, const _Float16* __restrict__ AL,
                   const _Float16* __restrict__ BH, const _Float16* __restrict__ BL,
                   _Float16* __restrict__ CH, _Float16* __restrict__ CL,
                   float cscale, float* __restrict__ deg) {
  // [buf][AH,AL,BH,BL][128 rows * 32 k], swizzled chunk layout:
  // chunk slot (row, kc') holds global (row, kc) with kc' = (kc + (row>>1)) & 3
  __shared__ __align__(16) _Float16 smem[2][4][128 * 32];

  const int t = threadIdx.x;
  const int lane = t & 63;
  const int w = t >> 6;
  const int wm = w >> 1, wn = w & 1;
  const int i0 = blockIdx.y * 128, j0 = blockIdx.x * 128;
  const long zo = (long)blockIdx.z * NNE;

  // staging: wave w owns tile w. LDS slot = linear lane -> (row=lane>>2, kc'=lane&3)
  // so the global source chunk must be kc = (kc' - (row>>1)) & 3.
  const _Float16* gsrc = (w == 0) ? AH : (w == 1) ? AL : (w == 2) ? BH : BL;
  const int rbase = (w < 2) ? i0 : j0;
  const int kc_st = (((lane & 3) - ((lane >> 3) & 3)) & 3) * 8;
  const _Float16* gp = gsrc + zo + (long)(rbase + (lane >> 2)) * N_NODES + kc_st;

  // fragment reads: row = (base16) + (lane&15), global kchunk = lane>>4.
  // swizzled chunk = ((lane>>4) + (row>>1)) & 3; base16 multiples of 16 drop out.
  const int fr = lane & 15;
  const int fkz = (((lane >> 4) + (fr >> 1)) & 3) * 8;
  const int aoff = (wm * 64 + fr) * 32 + fkz;
  const int boff = (wn * 64 + fr) * 32 + fkz;

  floatx4 acc[4][4];
  #pragma unroll
  for (int i = 0; i < 4; ++i)
    #pragma unroll
    for (int j = 0; j < 4; ++j) {
      floatx4 z = {0.f, 0.f, 0.f, 0.f};
      acc[i][j] = z;
    }

  // prologue: stage tile 0 into buf 0
  {
    _Float16* lb = &smem[0][w][0];
    #pragma unroll
    for (int q = 0; q < 8; ++q)
      async_cp16(gp + (long)q * (16 * N_NODES), lb + q * 512);
    gp += 32;
  }
  __syncthreads();

  for (int kt = 0; kt < N_NODES / 32; ++kt) {
    const int p = kt & 1;
    // prefetch next tile into the other buffer (stays in flight during compute)
    if (kt + 1 < N_NODES / 32) {
      _Float16* lb = &smem[p ^ 1][w][0];
      #pragma unroll
      for (int q = 0; q < 8; ++q)
        async_cp16(gp + (long)q * (16 * N_NODES), lb + q * 512);
      gp += 32;
    }

    const _Float16* base = &smem[p][0][0];
    half8_t ah[4], al[4], bh[4], bl[4];
    #pragma unroll
    for (int mt = 0; mt < 4; ++mt) {
      ah[mt] = *(const half8_t*)(base + aoff + mt * 512);
      al[mt] = *(const half8_t*)(base + 4096 + aoff + mt * 512);
    }
    #pragma unroll
    for (int nt = 0; nt < 4; ++nt) {
      bh[nt] = *(const half8_t*)(base + 8192 + boff + nt * 512);
      bl[nt] = *(const half8_t*)(base + 12288 + boff + nt * 512);
    }
    #pragma unroll
    for (int mt = 0; mt < 4; ++mt)
      #pragma unroll
      for (int nt = 0; nt < 4; ++nt) {
        acc[mt][nt] = __builtin_amdgcn_mfma_f32_16x16x32_f16(ah[mt], bh[nt], acc[mt][nt], 0, 0, 0);
        acc[mt][nt] = __builtin_amdgcn_mfma_f32_16x16x32_f16(al[mt], bh[nt], acc[mt][nt], 0, 0, 0);
        acc[mt][nt] = __builtin_amdgcn_mfma_f32_16x16x32_f16(ah[mt], bl[nt], acc[mt][nt], 0, 0, 0);
      }
    // one barrier per iter: drains prefetch (in flight all compute long) and
    // guards buf[p] against next iteration's overwrite.
    __syncthreads();
  }

  // epilogue: C/D layout col = lane&15, row = (lane>>4)*4 + reg
  const int er = (lane >> 4) * 4;
  const int ec = lane & 15;
  #pragma unroll
  for (int mt = 0; mt < 4; ++mt) {
    float s[4] = {0.f, 0.f, 0.f, 0.f};
    #pragma unroll
    for (int nt = 0; nt < 4; ++nt) {
      const int jb = j0 + wn * 64 + nt * 16 + ec;
      #pragma unroll
      for (int r = 0; r < 4; ++r) {
        float x = acc[mt][nt][r] * cscale;
        s[r] += x;
        _Float16 h = (_Float16)x;
        long o = zo + (long)(i0 + wm * 64 + mt * 16 + er + r) * N_NODES + jb;
        CH[o] = h;
        CL[o] = (_Float16)(x - (float)h);
      }
    }
    if (deg) {
      #pragma unroll
      for (int r = 0; r < 4; ++r) {
        s[r] += __shfl_xor(s[r], 1, 64);
        s[r] += __shfl_xor(s[r], 2, 64);
        s[r] += __shfl_xor(s[r], 4, 64);
        s[r] += __shfl_xor(s[r], 8, 64);
      }
      if (ec == 0) {
        float* dp = deg + (long)blockIdx.z * N_NODES + i0 + wm * 64 + mt * 16 + er;
        #pragma unroll
        for (int r = 0; r < 4; ++r) atomicAdd(dp + r, s[r]);
      }
    }
  }
}

// -- supd[c][m][f] = d[c][m]*support[m][f], d = 1/sqrt(1+256*deg); save dvec --
__global__ __launch_bounds__(256)
void supd_k(const float4* __restrict__ sup4, const float* __restrict__ deg,
            float* __restrict__ dvec, float4* __restrict__ out4, int c0) {
  const int c = c0 + blockIdx.y;
  const int idx = blockIdx.x * 256 + threadIdx.x;
  const int m = idx >> 5;
  float dm = 1.0f / sqrtf(1.0f + SH2_INV * deg[(long)c * N_NODES + m]);
  if ((idx & 31) == 0) dvec[(long)c * N_NODES + m] = dm;
  float4 v = sup4[idx];
  v.x *= dm; v.y *= dm; v.z *= dm; v.w *= dm;
  out4[(long)c * (N_NODES * 32) + idx] = v;
}

// --- out[:, c*128:(c+1)*128] = relu(dn*(SH2_INV*(H2s@supd) + supd_n) + b) ---
__global__ __launch_bounds__(256)
void gemm_out_k(const _Float16* __restrict__ H2H, const _Float16* __restrict__ H2L,
                const float* __restrict__ supd, const float* __restrict__ dvec,
                const float* __restrict__ bias, float* __restrict__ out, int c0) {
  const int t = threadIdx.x;
  const int c = c0 + blockIdx.z;
  const _Float16* A2H = H2H + (long)blockIdx.z * NNE;
  const _Float16* A2L = H2L + (long)blockIdx.z * NNE;
  const float* Bsup = supd + (long)c * N_NODES * 128;
  const float* dv   = dvec + (long)c * N_NODES;
  const int i0 = blockIdx.x * 32;

  __shared__ float As[32][36];
  __shared__ float Bs[32][128];

  const int arow = t >> 3;
  const int akq  = (t & 7) << 2;
  const int brow = t >> 5;
  const int bjq  = (t & 31) << 2;
  const int tx = t & 31, ty = t >> 5;

  float acc[4][4];
  #pragma unroll
  for (int r = 0; r < 4; ++r)
    #pragma unroll
    for (int s = 0; s < 4; ++s) acc[r][s] = 0.f;

  const int nk = N_NODES / 32;
  for (int kt = 0; kt < nk; ++kt) {
    const int k0 = kt * 32;
    __syncthreads();
    half4_t hh = *(const half4_t*)(A2H + (long)(i0 + arow) * N_NODES + k0 + akq);
    half4_t ll = *(const half4_t*)(A2L + (long)(i0 + arow) * N_NODES + k0 + akq);
    #pragma unroll
    for (int d = 0; d < 4; ++d)
      As[akq + d][arow] = (float)hh[d] + (float)ll[d];
    #pragma unroll
    for (int m = 0; m < 4; ++m)
      *(float4*)&Bs[brow + 8 * m][bjq] =
          *(const float4*)(Bsup + (long)(k0 + brow + 8 * m) * 128 + bjq);
    __syncthreads();
    #pragma unroll
    for (int k = 0; k < 32; ++k) {
      float av[4], bv[4];
      *(float4*)&av[0] = *(const float4*)&As[k][ty * 4];
      *(float4*)&bv[0] = *(const float4*)&Bs[k][tx * 4];
      #pragma unroll
      for (int r = 0; r < 4; ++r)
        #pragma unroll
        for (int s = 0; s < 4; ++s)
          acc[r][s] = fmaf(av[r], bv[s], acc[r][s]);
    }
  }
  #pragma unroll
  for (int r = 0; r < 4; ++r) {
    const int i = i0 + ty * 4 + r;
    const float dn = dv[i];
    float4 o;
    o.x = fmaxf(dn * (acc[r][0] * SH2_INV + Bsup[(long)i * 128 + tx * 4 + 0]) + bias[tx * 4 + 0], 0.f);
    o.y = fmaxf(dn * (acc[r][1] * SH2_INV + Bsup[(long)i * 128 + tx * 4 + 1]) + bias[tx * 4 + 1], 0.f);
    o.z = fmaxf(dn * (acc[r][2] * SH2_INV + Bsup[(long)i * 128 + tx * 4 + 2]) + bias[tx * 4 + 2], 0.f);
    o.w = fmaxf(dn * (acc[r][3] * SH2_INV + Bsup[(long)i * 128 + tx * 4 + 3]) + bias[tx * 4 + 3], 0.f);
    *(float4*)(out + (long)i * 512 + c * 128 + tx * 4) = o;
  }
}

extern "C" void kernel_launch(void* const* d_in, const int* in_sizes, int n_in,
                              void* d_out, int out_size, void* d_ws, size_t ws_size,
                              hipStream_t stream) {
  const float* A  = (const float*)d_in[0];
  const float* X  = (const float*)d_in[1];
  const float* w1 = (const float*)d_in[2];
  const float* w2 = (const float*)d_in[3];
  const float* w3 = (const float*)d_in[4];
  const float* gw = (const float*)d_in[5];
  const float* gb = (const float*)d_in[6];
  float* out = (float*)d_out;

  float* ws   = (float*)d_ws;
  float* fw   = ws;                              // 64 floats
  float* dvec = ws + 64;                         // 4*2048
  float* deg  = dvec + 4 * N_NODES;              // 4*2048
  float* sup  = deg + 4 * N_NODES;               // 2048*128
  float* supd = sup + (long)N_NODES * 128;       // 4*2048*128
  _Float16* arena = (_Float16*)(supd + (long)4 * N_NODES * 128);

  const long base_bytes = (long)(64 + 8 * N_NODES + (long)N_NODES * 128 +
                                 (long)4 * N_NODES * 128) * 4;
  int nc = 1;
  if ((long)ws_size >= base_bytes + 12L * 4 * NNE) nc = 4;
  else if ((long)ws_size >= base_bytes + 12L * 2 * NNE) nc = 2;

  _Float16* P1H = arena;
  _Float16* P1L = P1H + (long)nc * NNE;
  _Float16* P2H = P1L + (long)nc * NNE;
  _Float16* P2L = P2H + (long)nc * NNE;
  _Float16* P3H = P2L + (long)nc * NNE;
  _Float16* P3L = P3H + (long)nc * NNE;

  softmax3_k<<<1, 64, 0, stream>>>(w1, w2, w3, fw);
  support_k<<<N_NODES, 128, 0, stream>>>(X, gw, sup);
  hipMemsetAsync(deg, 0, 4 * N_NODES * sizeof(float), stream);

  for (int c0 = 0; c0 < 4; c0 += nc) {
    // Ha (row-major) -> P1, HbT (transposed) -> P2, single A pass
    mixAB_k<<<dim3(64, 64), 256, 0, stream>>>(A, fw, P1H, P1L, P2H, P2L, c0, nc);
    // H1 = Ha @ Hb -> P3 (|H1| < 2048 fits f16)
    gemm_nt_split<<<dim3(16, 16, nc), 256, 0, stream>>>(P1H, P1L, P2H, P2L, P3H, P3L,
                                                        1.0f, nullptr);
    // HcT -> P1
    mixT_split_k<<<dim3(64, 64), 256, 0, stream>>>(A, fw, P1H, P1L, c0, nc, 32);
    // H2s = (H1 @ Hc) * 2^-8 -> P2, fused rowsum -> deg
    gemm_nt_split<<<dim3(16, 16, nc), 256, 0, stream>>>(P3H, P3L, P1H, P1L, P2H, P2L,
                                                        SH2, deg + (long)c0 * N_NODES);
    // supd = d * support (d from deg), save dvec
    supd_k<<<dim3(256, nc), 256, 0, stream>>>((const float4*)sup, deg, dvec,
                                              (float4*)supd, c0);
    gemm_out_k<<<dim3(64, 1, nc), 256, 0, stream>>>(P2H, P2L, supd, dvec, gb, out, c0);
  }
}

// Round 5
// 480.473 us; speedup vs baseline: 3.5760x; 1.3965x over previous
//
#include <hip/hip_runtime.h>
#include <math.h>

#define N_NODES 2048
#define NNE ((long)N_NODES * N_NODES)   // elems per channel matrix
#define NNE4 (NNE / 4)

// f16 two-term split: x ~= h + l, h = f16(x), l = f16(x - h) true residual.
// Three MFMA products (hh, lh, hl) into ONE fp32 accumulator; dropped l*l
// term is ~2^-22 relative.
// Scale plan (all powers of 2, exact):
//   supdT' = (d .* support)^T * 2^13   (keeps f16 residuals normal)
//   M''    = Hc @ supdT'               (carries the 2^13; |M''| <~ 1400)
//   out    = d*( (H1@M'')*2^-13 + supd ) + b
#define SUPD_SCALE 8192.0f
#define SUPD_INV   (1.0f / 8192.0f)

typedef _Float16 half4_t __attribute__((ext_vector_type(4)));
typedef _Float16 half8_t __attribute__((ext_vector_type(8)));
typedef float    floatx4 __attribute__((ext_vector_type(4)));

__device__ __forceinline__ void async_cp16(const void* g, void* l) {
  // HW computes LDS dest = wave-uniform base + lane*16
  __builtin_amdgcn_global_load_lds((const __attribute__((address_space(1))) void*)g,
                                   (__attribute__((address_space(3))) void*)l,
                                   16, 0, 0);
}

// ---------------- softmax of the three 4x4 weight matrices ----------------
__global__ void softmax3_k(const float* __restrict__ w1,
                           const float* __restrict__ w2,
                           const float* __restrict__ w3,
                           float* __restrict__ fw) {
  int t = threadIdx.x;
  if (t < 12) {
    const float* src = (t < 4) ? w1 : (t < 8) ? w2 : w3;
    int r = t & 3;
    float v0 = src[r * 4 + 0], v1 = src[r * 4 + 1];
    float v2 = src[r * 4 + 2], v3 = src[r * 4 + 3];
    float m = fmaxf(fmaxf(v0, v1), fmaxf(v2, v3));
    float e0 = expf(v0 - m), e1 = expf(v1 - m), e2 = expf(v2 - m), e3 = expf(v3 - m);
    float inv = 1.0f / (e0 + e1 + e2 + e3);
    fw[t * 4 + 0] = e0 * inv; fw[t * 4 + 1] = e1 * inv;
    fw[t * 4 + 2] = e2 * inv; fw[t * 4 + 3] = e3 * inv;
  }
}

// ---------------- support = X @ gcn_w  [2048,256]@[256,128] ----------------
__global__ __launch_bounds__(128)
void support_k(const float* __restrict__ X, const float* __restrict__ W,
               float* __restrict__ sup) {
  __shared__ float Xs[256];
  const int t = threadIdx.x;
  const int m = blockIdx.x;
  Xs[t]       = X[(long)m * 256 + t];
  Xs[t + 128] = X[(long)m * 256 + t + 128];
  __syncthreads();
  float acc = 0.f;
  #pragma unroll 8
  for (int k = 0; k < 256; ++k) acc = fmaf(Xs[k], W[(long)k * 128 + t], acc);
  sup[(long)m * 128 + t] = acc;
}

// ---------------- per-edge-type row sums of A: rsA[e][r] -------------------
__global__ __launch_bounds__(256)
void rowsumA_k(const float* __restrict__ A, float* __restrict__ rsA) {
  const int t = threadIdx.x;
  const int r = blockIdx.x * 4 + (t >> 6);
  const int lane = t & 63;
  #pragma unroll
  for (int e = 0; e < 4; ++e) {
    const float* row = A + (long)e * NNE + (long)r * N_NODES;
    float s = 0.f;
    for (int k = lane; k < N_NODES; k += 64) s += row[k];
    for (int off = 32; off > 0; off >>= 1) s += __shfl_down(s, off, 64);
    if (lane == 0) rsA[e * N_NODES + r] = s;
  }
}

// ---- rc[c][j] = rowsum of Hc = sum_e fw3[c][e]*rsA[e][j]  (Hc @ ones) -----
__global__ __launch_bounds__(256)
void rc_k(const float* __restrict__ rsA, const float* __restrict__ fw,
          float* __restrict__ rc) {
  int j = blockIdx.x * 256 + threadIdx.x;
  float a0 = rsA[j], a1 = rsA[N_NODES + j];
  float a2 = rsA[2 * N_NODES + j], a3 = rsA[3 * N_NODES + j];
  #pragma unroll
  for (int c = 0; c < 4; ++c) {
    const float* w = fw + 32 + c * 4;
    rc[c * N_NODES + j] = w[0] * a0 + w[1] * a1 + w[2] * a2 + w[3] * a3;
  }
}

// -- fused: Ha (row-major split) AND HbT (transposed split) in one A pass ---
__global__ __launch_bounds__(256)
void mixAB_k(const float* __restrict__ A, const float* __restrict__ fw,
             _Float16* __restrict__ HaH, _Float16* __restrict__ HaL,
             _Float16* __restrict__ HbH, _Float16* __restrict__ HbL,
             int c0, int nc) {
  __shared__ _Float16 s1h[32][33], s1l[32][33];
  __shared__ _Float16 s2h[32][33], s2l[32][33];
  const int t = threadIdx.x;
  const int r0 = t >> 5, cc = t & 31;
  const int i0 = blockIdx.y * 32, j0 = blockIdx.x * 32;
  float a[4][4];
  #pragma unroll
  for (int e = 0; e < 4; ++e)
    #pragma unroll
    for (int m = 0; m < 4; ++m)
      a[e][m] = A[(long)e * NNE + (long)(i0 + r0 + 8 * m) * N_NODES + j0 + cc];

  const int rr = t >> 3, cq = (t & 7) * 4;
  for (int ci = 0; ci < nc; ++ci) {
    const float* wa = fw + (c0 + ci) * 4;
    const float* wb = fw + 16 + (c0 + ci) * 4;
    #pragma unroll
    for (int m = 0; m < 4; ++m) {
      float v1 = wa[0] * a[0][m] + wa[1] * a[1][m] + wa[2] * a[2][m] + wa[3] * a[3][m];
      float v2 = wb[0] * a[0][m] + wb[1] * a[1][m] + wb[2] * a[2][m] + wb[3] * a[3][m];
      _Float16 h1 = (_Float16)v1;
      s1h[r0 + 8 * m][cc] = h1;
      s1l[r0 + 8 * m][cc] = (_Float16)(v1 - (float)h1);
      _Float16 h2 = (_Float16)v2;
      s2h[r0 + 8 * m][cc] = h2;
      s2l[r0 + 8 * m][cc] = (_Float16)(v2 - (float)h2);
    }
    __syncthreads();
    half4_t oh, ol;
    #pragma unroll
    for (int d = 0; d < 4; ++d) { oh[d] = s1h[rr][cq + d]; ol[d] = s1l[rr][cq + d]; }
    long o1 = (long)ci * NNE + (long)(i0 + rr) * N_NODES + j0 + cq;
    *(half4_t*)(HaH + o1) = oh;
    *(half4_t*)(HaL + o1) = ol;
    #pragma unroll
    for (int d = 0; d < 4; ++d) { oh[d] = s2h[cq + d][rr]; ol[d] = s2l[cq + d][rr]; }
    long o2 = (long)ci * NNE + (long)(j0 + rr) * N_NODES + i0 + cq;
    *(half4_t*)(HbH + o2) = oh;
    *(half4_t*)(HbL + o2) = ol;
    __syncthreads();
  }
}

// ------- mix+split (row-major): O = split( sum_e fw[off+c][e] * A[e] ) ------
__global__ __launch_bounds__(256)
void mix_split_k(const float4* __restrict__ A4, const float* __restrict__ fw,
                 _Float16* __restrict__ OH, _Float16* __restrict__ OL,
                 int c0, int nc, int off) {
  long idx = (long)blockIdx.x * 256 + threadIdx.x;
  if (idx >= NNE4) return;
  float4 a0 = A4[idx];
  float4 a1 = A4[NNE4 + idx];
  float4 a2 = A4[2 * NNE4 + idx];
  float4 a3 = A4[3 * NNE4 + idx];
  for (int ci = 0; ci < nc; ++ci) {
    const float* wv = fw + off + (c0 + ci) * 4;
    float o[4];
    o[0] = wv[0] * a0.x + wv[1] * a1.x + wv[2] * a2.x + wv[3] * a3.x;
    o[1] = wv[0] * a0.y + wv[1] * a1.y + wv[2] * a2.y + wv[3] * a3.y;
    o[2] = wv[0] * a0.z + wv[1] * a1.z + wv[2] * a2.z + wv[3] * a3.z;
    o[3] = wv[0] * a0.w + wv[1] * a1.w + wv[2] * a2.w + wv[3] * a3.w;
    half4_t h, l;
    #pragma unroll
    for (int d = 0; d < 4; ++d) {
      _Float16 hh = (_Float16)o[d];
      h[d] = hh;
      l[d] = (_Float16)(o[d] - (float)hh);
    }
    *(half4_t*)(OH + (long)ci * NNE + 4 * idx) = h;
    *(half4_t*)(OL + (long)ci * NNE + 4 * idx) = l;
  }
}

// ------------- MFMA split-f16 GEMM (NT): C = (AH+AL)(BH+BL) ----------------
// Double-buffered LDS + XOR-swizzled 16B chunks (conflict-free, m136-verified).
// If deg != nullptr, accumulates rc-weighted rowsum: deg[z][i] += sum_j C[i,j]*rc[z][j].
__global__ __launch_bounds__(256, 2)
void gemm_nt_split(const _Float16* __restrict__ AH, const _Float16* __restrict__ AL,
                   const _Float16* __restrict__ BH, const _Float16* __restrict__ BL,
                   _Float16* __restrict__ CH, _Float16* __restrict__ CL,
                   const float* __restrict__ rc, float* __restrict__ deg) {
  __shared__ __align__(16) _Float16 smem[2][4][128 * 32];

  const int t = threadIdx.x;
  const int lane = t & 63;
  const int w = t >> 6;
  const int wm = w >> 1, wn = w & 1;
  const int i0 = blockIdx.y * 128, j0 = blockIdx.x * 128;
  const long zo = (long)blockIdx.z * NNE;

  const _Float16* gsrc = (w == 0) ? AH : (w == 1) ? AL : (w == 2) ? BH : BL;
  const int rbase = (w < 2) ? i0 : j0;
  const int kc_st = (((lane & 3) - ((lane >> 3) & 3)) & 3) * 8;
  const _Float16* gp = gsrc + zo + (long)(rbase + (lane >> 2)) * N_NODES + kc_st;

  const int fr = lane & 15;
  const int fkz = (((lane >> 4) + (fr >> 1)) & 3) * 8;
  const int aoff = (wm * 64 + fr) * 32 + fkz;
  const int boff = (wn * 64 + fr) * 32 + fkz;

  floatx4 acc[4][4];
  #pragma unroll
  for (int i = 0; i < 4; ++i)
    #pragma unroll
    for (int j = 0; j < 4; ++j) {
      floatx4 z = {0.f, 0.f, 0.f, 0.f};
      acc[i][j] = z;
    }

  {
    _Float16* lb = &smem[0][w][0];
    #pragma unroll
    for (int q = 0; q < 8; ++q)
      async_cp16(gp + (long)q * (16 * N_NODES), lb + q * 512);
    gp += 32;
  }
  __syncthreads();

  for (int kt = 0; kt < N_NODES / 32; ++kt) {
    const int p = kt & 1;
    if (kt + 1 < N_NODES / 32) {
      _Float16* lb = &smem[p ^ 1][w][0];
      #pragma unroll
      for (int q = 0; q < 8; ++q)
        async_cp16(gp + (long)q * (16 * N_NODES), lb + q * 512);
      gp += 32;
    }

    const _Float16* base = &smem[p][0][0];
    half8_t ah[4], al[4], bh[4], bl[4];
    #pragma unroll
    for (int mt = 0; mt < 4; ++mt) {
      ah[mt] = *(const half8_t*)(base + aoff + mt * 512);
      al[mt] = *(const half8_t*)(base + 4096 + aoff + mt * 512);
    }
    #pragma unroll
    for (int nt = 0; nt < 4; ++nt) {
      bh[nt] = *(const half8_t*)(base + 8192 + boff + nt * 512);
      bl[nt] = *(const half8_t*)(base + 12288 + boff + nt * 512);
    }
    #pragma unroll
    for (int mt = 0; mt < 4; ++mt)
      #pragma unroll
      for (int nt = 0; nt < 4; ++nt) {
        acc[mt][nt] = __builtin_amdgcn_mfma_f32_16x16x32_f16(ah[mt], bh[nt], acc[mt][nt], 0, 0, 0);
        acc[mt][nt] = __builtin_amdgcn_mfma_f32_16x16x32_f16(al[mt], bh[nt], acc[mt][nt], 0, 0, 0);
        acc[mt][nt] = __builtin_amdgcn_mfma_f32_16x16x32_f16(ah[mt], bl[nt], acc[mt][nt], 0, 0, 0);
      }
    __syncthreads();
  }

  // epilogue: C/D layout col = lane&15, row = (lane>>4)*4 + reg
  const int er = (lane >> 4) * 4;
  const int ec = lane & 15;
  float rcv[4];
  if (deg) {
    const float* rcz = rc + (long)blockIdx.z * N_NODES;
    #pragma unroll
    for (int nt = 0; nt < 4; ++nt)
      rcv[nt] = rcz[j0 + wn * 64 + nt * 16 + ec];
  }
  #pragma unroll
  for (int mt = 0; mt < 4; ++mt) {
    float s[4] = {0.f, 0.f, 0.f, 0.f};
    #pragma unroll
    for (int nt = 0; nt < 4; ++nt) {
      const int jb = j0 + wn * 64 + nt * 16 + ec;
      #pragma unroll
      for (int r = 0; r < 4; ++r) {
        float x = acc[mt][nt][r];
        if (deg) s[r] += x * rcv[nt];
        _Float16 h = (_Float16)x;
        long o = zo + (long)(i0 + wm * 64 + mt * 16 + er + r) * N_NODES + jb;
        CH[o] = h;
        CL[o] = (_Float16)(x - (float)h);
      }
    }
    if (deg) {
      #pragma unroll
      for (int r = 0; r < 4; ++r) {
        s[r] += __shfl_xor(s[r], 1, 64);
        s[r] += __shfl_xor(s[r], 2, 64);
        s[r] += __shfl_xor(s[r], 4, 64);
        s[r] += __shfl_xor(s[r], 8, 64);
      }
      if (ec == 0) {
        float* dp = deg + (long)blockIdx.z * N_NODES + i0 + wm * 64 + mt * 16 + er;
        #pragma unroll
        for (int r = 0; r < 4; ++r) atomicAdd(dp + r, s[r]);
      }
    }
  }
}

// -- supd[z][m][f] = d[c][m]*support[m][f], d = 1/sqrt(1+deg); save dvec ----
__global__ __launch_bounds__(256)
void supd_k(const float4* __restrict__ sup4, const float* __restrict__ deg,
            float* __restrict__ dvec, float4* __restrict__ out4, int c0) {
  const int c = c0 + blockIdx.y;
  const int idx = blockIdx.x * 256 + threadIdx.x;
  const int m = idx >> 5;
  float dm = 1.0f / sqrtf(1.0f + deg[(long)c * N_NODES + m]);
  if ((idx & 31) == 0) dvec[(long)c * N_NODES + m] = dm;
  float4 v = sup4[idx];
  v.x *= dm; v.y *= dm; v.z *= dm; v.w *= dm;
  out4[(long)blockIdx.y * (N_NODES * 32) + idx] = v;
}

// -- supdT'[z][f][m] = split( supd[z][m][f] * 2^13 ), LDS transpose ---------
__global__ __launch_bounds__(256)
void transposeSupd_k(const float* __restrict__ supd,
                     _Float16* __restrict__ TH, _Float16* __restrict__ TL) {
  __shared__ _Float16 sh[32][33], sl[32][33];
  const int t = threadIdx.x;
  const int z = blockIdx.z;
  const int m0 = blockIdx.x * 32, f0 = blockIdx.y * 32;
  const int r0 = t >> 5, col = t & 31;
  #pragma unroll
  for (int m = 0; m < 4; ++m) {
    float v = supd[(long)z * N_NODES * 128 + (long)(m0 + r0 + 8 * m) * 128 + f0 + col]
              * SUPD_SCALE;
    _Float16 h = (_Float16)v;
    sh[r0 + 8 * m][col] = h;
    sl[r0 + 8 * m][col] = (_Float16)(v - (float)h);
  }
  __syncthreads();
  const int rr = t >> 3, cq = (t & 7) * 4;
  half4_t oh, ol;
  #pragma unroll
  for (int d = 0; d < 4; ++d) { oh[d] = sh[cq + d][rr]; ol[d] = sl[cq + d][rr]; }
  long ob = (long)z * 128 * N_NODES + (long)(f0 + rr) * N_NODES + m0 + cq;
  *(half4_t*)(TH + ob) = oh;
  *(half4_t*)(TL + ob) = ol;
}

// ---- thin split-f16 GEMM with split-K: C[kc][z][i][f] = A[z]@B[z] chunk ---
// A [z][2048][2048] split halves; B [z][128][2048] split halves (NT);
// grid (4 K-chunks, 16 i-tiles, nc). C fp32 partials, no atomics.
__global__ __launch_bounds__(256, 2)
void gemm_thin_k(const _Float16* __restrict__ AH, const _Float16* __restrict__ AL,
                 const _Float16* __restrict__ BH, const _Float16* __restrict__ BL,
                 float* __restrict__ C) {
  __shared__ __align__(16) _Float16 smem[2][4][128 * 32];

  const int t = threadIdx.x;
  const int lane = t & 63;
  const int w = t >> 6;
  const int wm = w >> 1, wn = w & 1;
  const int i0 = blockIdx.y * 128;
  const int koff = blockIdx.x * 512;
  const int z = blockIdx.z;
  const long zoA = (long)z * NNE;
  const long zoB = (long)z * 128 * N_NODES;

  const _Float16* gsrc = (w == 0) ? (AH + zoA) : (w == 1) ? (AL + zoA)
                       : (w == 2) ? (BH + zoB) : (BL + zoB);
  const int rbase = (w < 2) ? i0 : 0;
  const int kc_st = (((lane & 3) - ((lane >> 3) & 3)) & 3) * 8;
  const _Float16* gp = gsrc + (long)(rbase + (lane >> 2)) * N_NODES + koff + kc_st;

  const int fr = lane & 15;
  const int fkz = (((lane >> 4) + (fr >> 1)) & 3) * 8;
  const int aoff = (wm * 64 + fr) * 32 + fkz;
  const int boff = (wn * 64 + fr) * 32 + fkz;

  floatx4 acc[4][4];
  #pragma unroll
  for (int i = 0; i < 4; ++i)
    #pragma unroll
    for (int j = 0; j < 4; ++j) {
      floatx4 zz = {0.f, 0.f, 0.f, 0.f};
      acc[i][j] = zz;
    }

  {
    _Float16* lb = &smem[0][w][0];
    #pragma unroll
    for (int q = 0; q < 8; ++q)
      async_cp16(gp + (long)q * (16 * N_NODES), lb + q * 512);
    gp += 32;
  }
  __syncthreads();

  const int NKI = 512 / 32;
  for (int kt = 0; kt < NKI; ++kt) {
    const int p = kt & 1;
    if (kt + 1 < NKI) {
      _Float16* lb = &smem[p ^ 1][w][0];
      #pragma unroll
      for (int q = 0; q < 8; ++q)
        async_cp16(gp + (long)q * (16 * N_NODES), lb + q * 512);
      gp += 32;
    }
    const _Float16* base = &smem[p][0][0];
    half8_t ah[4], al[4], bh[4], bl[4];
    #pragma unroll
    for (int mt = 0; mt < 4; ++mt) {
      ah[mt] = *(const half8_t*)(base + aoff + mt * 512);
      al[mt] = *(const half8_t*)(base + 4096 + aoff + mt * 512);
    }
    #pragma unroll
    for (int nt = 0; nt < 4; ++nt) {
      bh[nt] = *(const half8_t*)(base + 8192 + boff + nt * 512);
      bl[nt] = *(const half8_t*)(base + 12288 + boff + nt * 512);
    }
    #pragma unroll
    for (int mt = 0; mt < 4; ++mt)
      #pragma unroll
      for (int nt = 0; nt < 4; ++nt) {
        acc[mt][nt] = __builtin_amdgcn_mfma_f32_16x16x32_f16(ah[mt], bh[nt], acc[mt][nt], 0, 0, 0);
        acc[mt][nt] = __builtin_amdgcn_mfma_f32_16x16x32_f16(al[mt], bh[nt], acc[mt][nt], 0, 0, 0);
        acc[mt][nt] = __builtin_amdgcn_mfma_f32_16x16x32_f16(ah[mt], bl[nt], acc[mt][nt], 0, 0, 0);
      }
    __syncthreads();
  }

  const int er = (lane >> 4) * 4;
  const int ec = lane & 15;
  float* Cb = C + ((long)(blockIdx.x * gridDim.z + z) * N_NODES + i0) * 128;
  #pragma unroll
  for (int mt = 0; mt < 4; ++mt)
    #pragma unroll
    for (int nt = 0; nt < 4; ++nt) {
      const int f = wn * 64 + nt * 16 + ec;
      #pragma unroll
      for (int r = 0; r < 4; ++r)
        Cb[(long)(wm * 64 + mt * 16 + er + r) * 128 + f] = acc[mt][nt][r];
    }
}

// ---- MT[z][f][i] = split( sum_kc Mtmp[kc][z][i][f] ), LDS transpose -------
__global__ __launch_bounds__(256)
void combineM_k(const float* __restrict__ Mtmp, int nc,
                _Float16* __restrict__ TH, _Float16* __restrict__ TL) {
  __shared__ _Float16 sh[32][33], sl[32][33];
  const int t = threadIdx.x;
  const int z = blockIdx.z;
  const int i0 = blockIdx.x * 32, f0 = blockIdx.y * 32;
  const int r0 = t >> 5, col = t & 31;
  #pragma unroll
  for (int m = 0; m < 4; ++m) {
    long idx = ((long)z * N_NODES + i0 + r0 + 8 * m) * 128 + f0 + col;
    const long step = (long)nc * N_NODES * 128;
    float v = Mtmp[idx] + Mtmp[idx + step] + Mtmp[idx + 2 * step] + Mtmp[idx + 3 * step];
    _Float16 h = (_Float16)v;
    sh[r0 + 8 * m][col] = h;
    sl[r0 + 8 * m][col] = (_Float16)(v - (float)h);
  }
  __syncthreads();
  const int rr = t >> 3, cq = (t & 7) * 4;
  half4_t oh, ol;
  #pragma unroll
  for (int d = 0; d < 4; ++d) { oh[d] = sh[cq + d][rr]; ol[d] = sl[cq + d][rr]; }
  long ob = (long)z * 128 * N_NODES + (long)(f0 + rr) * N_NODES + i0 + cq;
  *(half4_t*)(TH + ob) = oh;
  *(half4_t*)(TL + ob) = ol;
}

// --- out[i][c*128+f] = relu( d*( (sum_kc OutTmp)*2^-13 + supd ) + b ) ------
__global__ __launch_bounds__(256)
void final_k(const float4* __restrict__ OutTmp, const float4* __restrict__ supd,
             const float* __restrict__ dvec, const float* __restrict__ bias,
             float* __restrict__ out, int c0, int nc) {
  const int t = threadIdx.x;
  const int z = blockIdx.y;
  const int c = c0 + z;
  const int idx = blockIdx.x * 256 + t;            // over N*128/4 = 65536
  const int i = idx >> 5;
  const int fq = (idx & 31) * 4;
  const long step4 = (long)nc * N_NODES * 32;      // float4 step per kc
  long b4 = (long)z * N_NODES * 32 + idx;
  float4 s0 = OutTmp[b4];
  float4 s1 = OutTmp[b4 + step4];
  float4 s2 = OutTmp[b4 + 2 * step4];
  float4 s3 = OutTmp[b4 + 3 * step4];
  float4 sp = supd[(long)z * N_NODES * 32 + idx];
  const float dn = dvec[(long)c * N_NODES + i];
  float4 o;
  o.x = fmaxf(dn * ((s0.x + s1.x + s2.x + s3.x) * SUPD_INV + sp.x) + bias[fq + 0], 0.f);
  o.y = fmaxf(dn * ((s0.y + s1.y + s2.y + s3.y) * SUPD_INV + sp.y) + bias[fq + 1], 0.f);
  o.z = fmaxf(dn * ((s0.z + s1.z + s2.z + s3.z) * SUPD_INV + sp.z) + bias[fq + 2], 0.f);
  o.w = fmaxf(dn * ((s0.w + s1.w + s2.w + s3.w) * SUPD_INV + sp.w) + bias[fq + 3], 0.f);
  *(float4*)(out + (long)i * 512 + c * 128 + fq) = o;
}

extern "C" void kernel_launch(void* const* d_in, const int* in_sizes, int n_in,
                              void* d_out, int out_size, void* d_ws, size_t ws_size,
                              hipStream_t stream) {
  const float* A  = (const float*)d_in[0];
  const float* X  = (const float*)d_in[1];
  const float* w1 = (const float*)d_in[2];
  const float* w2 = (const float*)d_in[3];
  const float* w3 = (const float*)d_in[4];
  const float* gw = (const float*)d_in[5];
  const float* gb = (const float*)d_in[6];
  float* out = (float*)d_out;

  // ---- workspace layout ----
  float* ws   = (float*)d_ws;
  float* fw   = ws;                       // 64
  float* rsA  = fw + 64;                  // 4*2048
  float* rc   = rsA + 4 * N_NODES;        // 4*2048
  float* deg  = rc + 4 * N_NODES;         // 4*2048
  float* dvec = deg + 4 * N_NODES;        // 4*2048
  float* sup  = dvec + 4 * N_NODES;       // 2048*128
  float* dyn  = sup + (long)N_NODES * 128;

  const long fixed_f = 64 + 16 * N_NODES + (long)N_NODES * 128;
  // per-channel: supd (N*128 f32) + Mtmp (4*N*128 f32, aliased as OutTmp)
  //            + 6 big f16 (NNE each) + supdT pair + MT pair (128*N each)
  const long per_f32 = 5L * N_NODES * 128;
  const long per_f16 = 6L * NNE + 4L * 128 * N_NODES;
  auto need = [&](int nc) {
    return (fixed_f + (long)nc * per_f32) * 4 + (long)nc * per_f16 * 2;
  };
  int nc = 1;
  if ((long)ws_size >= need(4)) nc = 4;
  else if ((long)ws_size >= need(2)) nc = 2;

  float* supd = dyn;                                   // [nc][2048][128]
  float* Mtmp = supd + (long)nc * N_NODES * 128;       // [4][nc][2048][128] (also OutTmp)
  _Float16* arena = (_Float16*)(Mtmp + 4L * nc * N_NODES * 128);
  _Float16* P1H = arena;                               // Ha, later Hc
  _Float16* P1L = P1H + (long)nc * NNE;
  _Float16* P2H = P1L + (long)nc * NNE;                // HbT
  _Float16* P2L = P2H + (long)nc * NNE;
  _Float16* P3H = P2L + (long)nc * NNE;                // H1
  _Float16* P3L = P3H + (long)nc * NNE;
  _Float16* sTH = P3L + (long)nc * NNE;                // supdT' [nc][128][2048]
  _Float16* sTL = sTH + (long)nc * 128 * N_NODES;
  _Float16* MTH = sTL + (long)nc * 128 * N_NODES;      // M''^T  [nc][128][2048]
  _Float16* MTL = MTH + (long)nc * 128 * N_NODES;

  softmax3_k<<<1, 64, 0, stream>>>(w1, w2, w3, fw);
  support_k<<<N_NODES, 128, 0, stream>>>(X, gw, sup);
  rowsumA_k<<<N_NODES / 4, 256, 0, stream>>>(A, rsA);
  rc_k<<<N_NODES / 256, 256, 0, stream>>>(rsA, fw, rc);
  hipMemsetAsync(deg, 0, 4 * N_NODES * sizeof(float), stream);

  for (int c0 = 0; c0 < 4; c0 += nc) {
    // Ha (row) -> P1, HbT (transposed) -> P2, single A pass
    mixAB_k<<<dim3(64, 64), 256, 0, stream>>>(A, fw, P1H, P1L, P2H, P2L, c0, nc);
    // H1 = Ha @ Hb -> P3; fused deg[i] += sum_j H1[i,j]*rc[j]
    gemm_nt_split<<<dim3(16, 16, nc), 256, 0, stream>>>(
        P1H, P1L, P2H, P2L, P3H, P3L, rc + (long)c0 * N_NODES,
        deg + (long)c0 * N_NODES);
    // Hc (row-major split) -> P1 (Ha dead)
    mix_split_k<<<4096, 256, 0, stream>>>((const float4*)A, fw, P1H, P1L, c0, nc, 32);
    // supd = d .* support  (d from deg)
    supd_k<<<dim3(256, nc), 256, 0, stream>>>((const float4*)sup, deg, dvec,
                                              (float4*)supd, c0);
    // supdT' = (supd * 2^13)^T split
    transposeSupd_k<<<dim3(64, 4, nc), 256, 0, stream>>>(supd, sTH, sTL);
    // M'' = Hc @ supdT'  (split-K partials)
    gemm_thin_k<<<dim3(4, 16, nc), 256, 0, stream>>>(P1H, P1L, sTH, sTL, Mtmp);
    // MT = split( sum_kc M'' ) transposed
    combineM_k<<<dim3(64, 4, nc), 256, 0, stream>>>(Mtmp, nc, MTH, MTL);
    // OutTmp = H1 @ M''  (split-K partials; reuses Mtmp storage)
    gemm_thin_k<<<dim3(4, 16, nc), 256, 0, stream>>>(P3H, P3L, MTH, MTL, Mtmp);
    // out = relu( d*(OutTmp*2^-13 + supd) + b )
    final_k<<<dim3(256, nc), 256, 0, stream>>>((const float4*)Mtmp,
                                               (const float4*)supd, dvec, gb,
                                               out, c0, nc);
  }
}

// Round 6
// 314.530 us; speedup vs baseline: 5.4627x; 1.5276x over previous
//
#include <hip/hip_runtime.h>
#include <math.h>

#define N_NODES 2048
#define NNE ((long)N_NODES * N_NODES)   // elems per channel matrix
#define NNE4 (NNE / 4)

// f16 two-term split: x ~= h + l (true residual). Three MFMA products
// (hh, lh, hl) into ONE fp32 accumulator; dropped l*l term ~2^-22 relative.
// Scale chain (all powers of 2, exact):
//   V0' = supd * 2^13                       (typ ~2, residuals normal)
//   T0  = Hc@V0'  -> scaled by sT0[f] = 2^(10-ilogb(cn0[f])), cn0=sum_m|V0'|
//   T1  = Hb@T0'  -> scaled by sT1[f] = 2^(10-ilogb(cn1[f])), cn1=sum_j|T0'|
//   T2  = Ha@T1'  (fp32); out = d*(T2*2^(i0+i1-33) + supd) + b
// Bounds are HARD because every mixed matrix has entries in [0,1].
#define SUPD_SCALE 8192.0f

typedef _Float16 half4_t __attribute__((ext_vector_type(4)));
typedef _Float16 half8_t __attribute__((ext_vector_type(8)));
typedef float    floatx4 __attribute__((ext_vector_type(4)));

__device__ __forceinline__ void async_cp16(const void* g, void* l) {
  __builtin_amdgcn_global_load_lds((const __attribute__((address_space(1))) void*)g,
                                   (__attribute__((address_space(3))) void*)l,
                                   16, 0, 0);
}

__device__ __forceinline__ float colscale_from(float cn) {
  return exp2f((float)(10 - ilogbf(fmaxf(cn, 1e-37f))));
}

// ---------------- softmax of the three 4x4 weight matrices ----------------
__global__ void softmax3_k(const float* __restrict__ w1,
                           const float* __restrict__ w2,
                           const float* __restrict__ w3,
                           float* __restrict__ fw) {
  int t = threadIdx.x;
  if (t < 12) {
    const float* src = (t < 4) ? w1 : (t < 8) ? w2 : w3;
    int r = t & 3;
    float v0 = src[r * 4 + 0], v1 = src[r * 4 + 1];
    float v2 = src[r * 4 + 2], v3 = src[r * 4 + 3];
    float m = fmaxf(fmaxf(v0, v1), fmaxf(v2, v3));
    float e0 = expf(v0 - m), e1 = expf(v1 - m), e2 = expf(v2 - m), e3 = expf(v3 - m);
    float inv = 1.0f / (e0 + e1 + e2 + e3);
    fw[t * 4 + 0] = e0 * inv; fw[t * 4 + 1] = e1 * inv;
    fw[t * 4 + 2] = e2 * inv; fw[t * 4 + 3] = e3 * inv;
  }
}

// ---------------- support = X @ gcn_w  [2048,256]@[256,128] ----------------
__global__ __launch_bounds__(128)
void support_k(const float* __restrict__ X, const float* __restrict__ W,
               float* __restrict__ sup) {
  __shared__ float Xs[256];
  const int t = threadIdx.x;
  const int m = blockIdx.x;
  Xs[t]       = X[(long)m * 256 + t];
  Xs[t + 128] = X[(long)m * 256 + t + 128];
  __syncthreads();
  float acc = 0.f;
  #pragma unroll 8
  for (int k = 0; k < 256; ++k) acc = fmaf(Xs[k], W[(long)k * 128 + t], acc);
  sup[(long)m * 128 + t] = acc;
}

// ---- rc[c][r] = sum_e fw3[c][e] * rowsum(A_e)[r]   (one A pass) ----------
__global__ __launch_bounds__(256)
void rc_from_A_k(const float* __restrict__ A, const float* __restrict__ fw,
                 float* __restrict__ rc) {
  const int wave = threadIdx.x >> 6, lane = threadIdx.x & 63;
  const int r = blockIdx.x * 4 + wave;
  float se[4];
  #pragma unroll
  for (int e = 0; e < 4; ++e) {
    const float4* row = (const float4*)(A + (long)e * NNE + (long)r * N_NODES);
    float s = 0.f;
    for (int j4 = lane; j4 < 512; j4 += 64) {
      float4 a = row[j4];
      s += (a.x + a.y) + (a.z + a.w);
    }
    for (int o = 32; o > 0; o >>= 1) s += __shfl_down(s, o, 64);
    se[e] = s;
  }
  if (lane == 0) {
    #pragma unroll
    for (int c = 0; c < 4; ++c)
      rc[c * N_NODES + r] = fw[32 + c * 4 + 0] * se[0] + fw[32 + c * 4 + 1] * se[1] +
                            fw[32 + c * 4 + 2] * se[2] + fw[32 + c * 4 + 3] * se[3];
  }
}

// -- vout[c][r] = sum_e fw[off+c*4+e] * (A_e @ vin[c])[r]  (fp32, one A pass)
__global__ __launch_bounds__(256)
void matvecA_k(const float* __restrict__ A, const float* __restrict__ fw, int off,
               const float* __restrict__ vin, float* __restrict__ vout) {
  __shared__ float vs[4 * 2048];
  const int t = threadIdx.x;
  for (int i = t; i < 4 * 2048; i += 256) vs[i] = vin[i];
  __syncthreads();
  const int wave = t >> 6, lane = t & 63;
  const int r = blockIdx.x * 4 + wave;
  float acc[4][4] = {{0.f}};
  #pragma unroll
  for (int e = 0; e < 4; ++e) {
    const float4* row = (const float4*)(A + (long)e * NNE + (long)r * N_NODES);
    for (int j4 = lane; j4 < 512; j4 += 64) {
      float4 a = row[j4];
      #pragma unroll
      for (int c = 0; c < 4; ++c) {
        const float4 v = *(const float4*)&vs[c * 2048 + j4 * 4];
        acc[e][c] += (a.x * v.x + a.y * v.y) + (a.z * v.z + a.w * v.w);
      }
    }
  }
  #pragma unroll
  for (int e = 0; e < 4; ++e)
    #pragma unroll
    for (int c = 0; c < 4; ++c)
      for (int o = 32; o > 0; o >>= 1) acc[e][c] += __shfl_down(acc[e][c], o, 64);
  if (lane == 0) {
    #pragma unroll
    for (int c = 0; c < 4; ++c) {
      float s = fw[off + c * 4 + 0] * acc[0][c] + fw[off + c * 4 + 1] * acc[1][c] +
                fw[off + c * 4 + 2] * acc[2][c] + fw[off + c * 4 + 3] * acc[3][c];
      vout[c * N_NODES + r] = s;
    }
  }
}

// -- one A pass -> Ha, Hb, Hc split row-major (no transposes needed) --------
__global__ __launch_bounds__(256)
void mix3_k(const float4* __restrict__ A4, const float* __restrict__ fw,
            _Float16* __restrict__ HaH, _Float16* __restrict__ HaL,
            _Float16* __restrict__ HbH, _Float16* __restrict__ HbL,
            _Float16* __restrict__ HcH, _Float16* __restrict__ HcL,
            int c0, int nc) {
  long idx = (long)blockIdx.x * 256 + threadIdx.x;
  float4 a0 = A4[idx];
  float4 a1 = A4[NNE4 + idx];
  float4 a2 = A4[2 * NNE4 + idx];
  float4 a3 = A4[3 * NNE4 + idx];
  for (int ci = 0; ci < nc; ++ci) {
    _Float16* OH[3] = {HaH, HbH, HcH};
    _Float16* OL[3] = {HaL, HbL, HcL};
    #pragma unroll
    for (int s = 0; s < 3; ++s) {
      const float* wv = fw + s * 16 + (c0 + ci) * 4;
      float o[4];
      o[0] = wv[0] * a0.x + wv[1] * a1.x + wv[2] * a2.x + wv[3] * a3.x;
      o[1] = wv[0] * a0.y + wv[1] * a1.y + wv[2] * a2.y + wv[3] * a3.y;
      o[2] = wv[0] * a0.z + wv[1] * a1.z + wv[2] * a2.z + wv[3] * a3.z;
      o[3] = wv[0] * a0.w + wv[1] * a1.w + wv[2] * a2.w + wv[3] * a3.w;
      half4_t h, l;
      #pragma unroll
      for (int d = 0; d < 4; ++d) {
        _Float16 hh = (_Float16)o[d];
        h[d] = hh;
        l[d] = (_Float16)(o[d] - (float)hh);
      }
      *(half4_t*)(OH[s] + (long)ci * NNE + 4 * idx) = h;
      *(half4_t*)(OL[s] + (long)ci * NNE + 4 * idx) = l;
    }
  }
}

// -- supd[z][m][f] = d[c][m]*support[m][f], d = 1/sqrt(1+deg); save dvec ----
__global__ __launch_bounds__(256)
void supd_k(const float4* __restrict__ sup4, const float* __restrict__ deg,
            float* __restrict__ dvec, float4* __restrict__ out4, int c0) {
  const int c = c0 + blockIdx.y;
  const int idx = blockIdx.x * 256 + threadIdx.x;
  const int m = idx >> 5;
  float dm = 1.0f / sqrtf(1.0f + deg[(long)c * N_NODES + m]);
  if ((idx & 31) == 0) dvec[(long)c * N_NODES + m] = dm;
  float4 v = sup4[idx];
  v.x *= dm; v.y *= dm; v.z *= dm; v.w *= dm;
  out4[(long)blockIdx.y * (N_NODES * 32) + idx] = v;
}

// -- VT[z][f][m] = split( supd[z][m][f]*2^13 ); cn0[z][f] += sum_m |val| ----
__global__ __launch_bounds__(256)
void transposeV_k(const float* __restrict__ supd,
                  _Float16* __restrict__ TH, _Float16* __restrict__ TL,
                  float* __restrict__ cn0) {
  __shared__ _Float16 sh[32][33], sl[32][33];
  __shared__ float red[8][32];
  const int t = threadIdx.x;
  const int z = blockIdx.z;
  const int m0 = blockIdx.x * 32, f0 = blockIdx.y * 32;
  const int r0 = t >> 5, col = t & 31;
  float part = 0.f;
  #pragma unroll
  for (int m = 0; m < 4; ++m) {
    float v = supd[(long)z * N_NODES * 128 + (long)(m0 + r0 + 8 * m) * 128 + f0 + col]
              * SUPD_SCALE;
    _Float16 h = (_Float16)v;
    sh[r0 + 8 * m][col] = h;
    sl[r0 + 8 * m][col] = (_Float16)(v - (float)h);
    part += fabsf(v);
  }
  red[r0][col] = part;
  __syncthreads();
  if (t < 32) {
    float s = 0.f;
    #pragma unroll
    for (int q = 0; q < 8; ++q) s += red[q][t];
    atomicAdd(&cn0[(long)z * 128 + f0 + t], s);
  }
  const int rr = t >> 3, cq = (t & 7) * 4;
  half4_t oh, ol;
  #pragma unroll
  for (int d = 0; d < 4; ++d) { oh[d] = sh[cq + d][rr]; ol[d] = sl[cq + d][rr]; }
  long ob = (long)z * 128 * N_NODES + (long)(f0 + rr) * N_NODES + m0 + cq;
  *(half4_t*)(TH + ob) = oh;
  *(half4_t*)(TL + ob) = ol;
}

// ---- thin split-f16 GEMM, split-K: partials[kc][z][i][f] = A[z]@B[z] ------
// A [z][2048][2048] split halves; B [z][128][2048] split halves (NT).
__global__ __launch_bounds__(256, 2)
void gemm_thin_k(const _Float16* __restrict__ AH, const _Float16* __restrict__ AL,
                 const _Float16* __restrict__ BH, const _Float16* __restrict__ BL,
                 float* __restrict__ C) {
  __shared__ __align__(16) _Float16 smem[2][4][128 * 32];

  const int t = threadIdx.x;
  const int lane = t & 63;
  const int w = t >> 6;
  const int wm = w >> 1, wn = w & 1;
  const int i0 = blockIdx.y * 128;
  const int koff = blockIdx.x * 512;
  const int z = blockIdx.z;
  const long zoA = (long)z * NNE;
  const long zoB = (long)z * 128 * N_NODES;

  const _Float16* gsrc = (w == 0) ? (AH + zoA) : (w == 1) ? (AL + zoA)
                       : (w == 2) ? (BH + zoB) : (BL + zoB);
  const int rbase = (w < 2) ? i0 : 0;
  const int kc_st = (((lane & 3) - ((lane >> 3) & 3)) & 3) * 8;
  const _Float16* gp = gsrc + (long)(rbase + (lane >> 2)) * N_NODES + koff + kc_st;

  const int fr = lane & 15;
  const int fkz = (((lane >> 4) + (fr >> 1)) & 3) * 8;
  const int aoff = (wm * 64 + fr) * 32 + fkz;
  const int boff = (wn * 64 + fr) * 32 + fkz;

  floatx4 acc[4][4];
  #pragma unroll
  for (int i = 0; i < 4; ++i)
    #pragma unroll
    for (int j = 0; j < 4; ++j) {
      floatx4 zz = {0.f, 0.f, 0.f, 0.f};
      acc[i][j] = zz;
    }

  {
    _Float16* lb = &smem[0][w][0];
    #pragma unroll
    for (int q = 0; q < 8; ++q)
      async_cp16(gp + (long)q * (16 * N_NODES), lb + q * 512);
    gp += 32;
  }
  __syncthreads();

  const int NKI = 512 / 32;
  for (int kt = 0; kt < NKI; ++kt) {
    const int p = kt & 1;
    if (kt + 1 < NKI) {
      _Float16* lb = &smem[p ^ 1][w][0];
      #pragma unroll
      for (int q = 0; q < 8; ++q)
        async_cp16(gp + (long)q * (16 * N_NODES), lb + q * 512);
      gp += 32;
    }
    const _Float16* base = &smem[p][0][0];
    half8_t ah[4], al[4], bh[4], bl[4];
    #pragma unroll
    for (int mt = 0; mt < 4; ++mt) {
      ah[mt] = *(const half8_t*)(base + aoff + mt * 512);
      al[mt] = *(const half8_t*)(base + 4096 + aoff + mt * 512);
    }
    #pragma unroll
    for (int nt = 0; nt < 4; ++nt) {
      bh[nt] = *(const half8_t*)(base + 8192 + boff + nt * 512);
      bl[nt] = *(const half8_t*)(base + 12288 + boff + nt * 512);
    }
    #pragma unroll
    for (int mt = 0; mt < 4; ++mt)
      #pragma unroll
      for (int nt = 0; nt < 4; ++nt) {
        acc[mt][nt] = __builtin_amdgcn_mfma_f32_16x16x32_f16(ah[mt], bh[nt], acc[mt][nt], 0, 0, 0);
        acc[mt][nt] = __builtin_amdgcn_mfma_f32_16x16x32_f16(al[mt], bh[nt], acc[mt][nt], 0, 0, 0);
        acc[mt][nt] = __builtin_amdgcn_mfma_f32_16x16x32_f16(ah[mt], bl[nt], acc[mt][nt], 0, 0, 0);
      }
    __syncthreads();
  }

  const int er = (lane >> 4) * 4;
  const int ec = lane & 15;
  float* Cb = C + ((long)(blockIdx.x * gridDim.z + z) * N_NODES + i0) * 128;
  #pragma unroll
  for (int mt = 0; mt < 4; ++mt)
    #pragma unroll
    for (int nt = 0; nt < 4; ++nt) {
      const int f = wn * 64 + nt * 16 + ec;
      #pragma unroll
      for (int r = 0; r < 4; ++r)
        Cb[(long)(wm * 64 + mt * 16 + er + r) * 128 + f] = acc[mt][nt][r];
    }
}

// -- T'[z][f][j] = split( (sum_kc P[kc][z][j][f]) * s(cn_in[z][f]) ) --------
// optionally accumulates cn_out[z][f] += sum_j |scaled val|
__global__ __launch_bounds__(256)
void combineT_k(const float* __restrict__ P, int nc,
                const float* __restrict__ cn_in, float* __restrict__ cn_out,
                _Float16* __restrict__ TH, _Float16* __restrict__ TL) {
  __shared__ _Float16 sh[32][33], sl[32][33];
  __shared__ float red[8][32];
  const int t = threadIdx.x;
  const int z = blockIdx.z;
  const int j0 = blockIdx.x * 32, f0 = blockIdx.y * 32;
  const int r0 = t >> 5, col = t & 31;
  const float s = colscale_from(cn_in[(long)z * 128 + f0 + col]);
  const long step = (long)nc * N_NODES * 128;
  float part = 0.f;
  #pragma unroll
  for (int m = 0; m < 4; ++m) {
    long idx = ((long)z * N_NODES + j0 + r0 + 8 * m) * 128 + f0 + col;
    float v = ((P[idx] + P[idx + step]) + (P[idx + 2 * step] + P[idx + 3 * step])) * s;
    _Float16 h = (_Float16)v;
    sh[r0 + 8 * m][col] = h;
    sl[r0 + 8 * m][col] = (_Float16)(v - (float)h);
    part += fabsf(v);
  }
  if (cn_out) red[r0][col] = part;
  __syncthreads();
  if (cn_out && t < 32) {
    float ss = 0.f;
    #pragma unroll
    for (int q = 0; q < 8; ++q) ss += red[q][t];
    atomicAdd(&cn_out[(long)z * 128 + f0 + t], ss);
  }
  const int rr = t >> 3, cq = (t & 7) * 4;
  half4_t oh, ol;
  #pragma unroll
  for (int d = 0; d < 4; ++d) { oh[d] = sh[cq + d][rr]; ol[d] = sl[cq + d][rr]; }
  long ob = (long)z * 128 * N_NODES + (long)(f0 + rr) * N_NODES + j0 + cq;
  *(half4_t*)(TH + ob) = oh;
  *(half4_t*)(TL + ob) = ol;
}

// --- out[i][c*128+f] = relu( d*( T2sum * 2^(i0+i1-33) + supd ) + b ) -------
__global__ __launch_bounds__(256)
void final_k(const float4* __restrict__ T2, const float4* __restrict__ supd,
             const float* __restrict__ dvec, const float* __restrict__ cn0,
             const float* __restrict__ cn1, const float* __restrict__ bias,
             float* __restrict__ out, int c0, int nc) {
  const int t = threadIdx.x;
  const int z = blockIdx.y;
  const int c = c0 + z;
  const int idx = blockIdx.x * 256 + t;
  const int i = idx >> 5;
  const int fq = (idx & 31) * 4;
  const long step4 = (long)nc * N_NODES * 32;
  long b4 = (long)z * N_NODES * 32 + idx;
  float4 s0 = T2[b4];
  float4 s1 = T2[b4 + step4];
  float4 s2 = T2[b4 + 2 * step4];
  float4 s3 = T2[b4 + 3 * step4];
  float4 sp = supd[(long)z * N_NODES * 32 + idx];
  const float dn = dvec[(long)c * N_NODES + i];
  float inv[4];
  #pragma unroll
  for (int d = 0; d < 4; ++d) {
    int i0 = ilogbf(fmaxf(cn0[(long)z * 128 + fq + d], 1e-37f));
    int i1 = ilogbf(fmaxf(cn1[(long)z * 128 + fq + d], 1e-37f));
    inv[d] = exp2f((float)(i0 + i1 - 33));
  }
  float4 o;
  o.x = fmaxf(dn * (((s0.x + s1.x) + (s2.x + s3.x)) * inv[0] + sp.x) + bias[fq + 0], 0.f);
  o.y = fmaxf(dn * (((s0.y + s1.y) + (s2.y + s3.y)) * inv[1] + sp.y) + bias[fq + 1], 0.f);
  o.z = fmaxf(dn * (((s0.z + s1.z) + (s2.z + s3.z)) * inv[2] + sp.z) + bias[fq + 2], 0.f);
  o.w = fmaxf(dn * (((s0.w + s1.w) + (s2.w + s3.w)) * inv[3] + sp.w) + bias[fq + 3], 0.f);
  *(float4*)(out + (long)i * 512 + c * 128 + fq) = o;
}

extern "C" void kernel_launch(void* const* d_in, const int* in_sizes, int n_in,
                              void* d_out, int out_size, void* d_ws, size_t ws_size,
                              hipStream_t stream) {
  const float* A  = (const float*)d_in[0];
  const float* X  = (const float*)d_in[1];
  const float* w1 = (const float*)d_in[2];
  const float* w2 = (const float*)d_in[3];
  const float* w3 = (const float*)d_in[4];
  const float* gw = (const float*)d_in[5];
  const float* gb = (const float*)d_in[6];
  float* out = (float*)d_out;

  // ---- workspace layout (floats first, then f16 arena; all 16B aligned) ----
  float* ws   = (float*)d_ws;
  float* fw   = ws;                        // 64
  float* rc   = fw + 64;                   // 4*2048
  float* v1   = rc + 4 * N_NODES;          // 4*2048
  float* deg  = v1 + 4 * N_NODES;          // 4*2048
  float* dvec = deg + 4 * N_NODES;         // 4*2048
  float* sup  = dvec + 4 * N_NODES;        // 2048*128
  float* dyn  = sup + (long)N_NODES * 128;

  const long fixed_f = 64 + 16 * N_NODES + (long)N_NODES * 128;
  const long per_f32 = 5L * N_NODES * 128 + 256;          // supd + 4x partials + cn0/cn1
  const long per_f16 = 6L * NNE + 6L * 128 * N_NODES;     // 3 split matrices + 3 split thin
  auto need = [&](int nc) {
    return (fixed_f + (long)nc * per_f32) * 4 + (long)nc * per_f16 * 2;
  };
  int nc = 1;
  if ((long)ws_size >= need(4)) nc = 4;
  else if ((long)ws_size >= need(2)) nc = 2;

  float* cn0  = dyn;                                   // [nc][128]
  float* cn1  = cn0 + (long)nc * 128;                  // [nc][128]
  float* supd = cn1 + (long)nc * 128;                  // [nc][2048][128]
  float* Mtmp = supd + (long)nc * N_NODES * 128;       // [4][nc][2048][128]
  _Float16* arena = (_Float16*)(Mtmp + 4L * nc * N_NODES * 128);
  _Float16* HaH = arena;
  _Float16* HaL = HaH + (long)nc * NNE;
  _Float16* HbH = HaL + (long)nc * NNE;
  _Float16* HbL = HbH + (long)nc * NNE;
  _Float16* HcH = HbL + (long)nc * NNE;
  _Float16* HcL = HcH + (long)nc * NNE;
  _Float16* VTH = HcL + (long)nc * NNE;                // [nc][128][2048]
  _Float16* VTL = VTH + (long)nc * 128 * N_NODES;
  _Float16* T0H = VTL + (long)nc * 128 * N_NODES;
  _Float16* T0L = T0H + (long)nc * 128 * N_NODES;
  _Float16* T1H = T0L + (long)nc * 128 * N_NODES;
  _Float16* T1L = T1H + (long)nc * 128 * N_NODES;

  // ---- channel-independent prework ----
  softmax3_k<<<1, 64, 0, stream>>>(w1, w2, w3, fw);
  support_k<<<N_NODES, 128, 0, stream>>>(X, gw, sup);
  rc_from_A_k<<<N_NODES / 4, 256, 0, stream>>>(A, fw, rc);       // rc = Hc@1
  matvecA_k<<<N_NODES / 4, 256, 0, stream>>>(A, fw, 16, rc, v1); // v1 = Hb@rc
  matvecA_k<<<N_NODES / 4, 256, 0, stream>>>(A, fw, 0, v1, deg); // deg = Ha@v1

  for (int c0 = 0; c0 < 4; c0 += nc) {
    hipMemsetAsync(cn0, 0, 2L * nc * 128 * sizeof(float), stream);  // cn0+cn1
    // Ha/Hb/Hc split row-major, one A pass
    mix3_k<<<(int)(NNE4 / 256), 256, 0, stream>>>((const float4*)A, fw,
                                                  HaH, HaL, HbH, HbL, HcH, HcL,
                                                  c0, nc);
    // supd = d .* support
    supd_k<<<dim3(256, nc), 256, 0, stream>>>((const float4*)sup, deg, dvec,
                                              (float4*)supd, c0);
    // VT = (supd*2^13)^T split, cn0 = col 1-norms
    transposeV_k<<<dim3(64, 4, nc), 256, 0, stream>>>(supd, VTH, VTL, cn0);
    // T0 = Hc @ VT
    gemm_thin_k<<<dim3(4, 16, nc), 256, 0, stream>>>(HcH, HcL, VTH, VTL, Mtmp);
    combineT_k<<<dim3(64, 4, nc), 256, 0, stream>>>(Mtmp, nc, cn0, cn1, T0H, T0L);
    // T1 = Hb @ T0'
    gemm_thin_k<<<dim3(4, 16, nc), 256, 0, stream>>>(HbH, HbL, T0H, T0L, Mtmp);
    combineT_k<<<dim3(64, 4, nc), 256, 0, stream>>>(Mtmp, nc, cn1, nullptr, T1H, T1L);
    // T2 = Ha @ T1'  (fp32 partials)
    gemm_thin_k<<<dim3(4, 16, nc), 256, 0, stream>>>(HaH, HaL, T1H, T1L, Mtmp);
    // out = relu( d*(T2*inv + supd) + b )
    final_k<<<dim3(256, nc), 256, 0, stream>>>((const float4*)Mtmp,
                                               (const float4*)supd, dvec,
                                               cn0, cn1, gb, out, c0, nc);
  }
}